// Round 14
// baseline (897.902 us; speedup 1.0000x reference)
//
#include <hip/hip_runtime.h>
#include <hip/hip_bf16.h>
#include <math.h>

#define N_NODES 20000
#define N_EDGES 320000
#define NTILES  5000   // N_EDGES / 64
#define HD 128
#define RD 50
#define NL 6
#define CUTV 5.0f
#define PI_F 3.14159265358979323846f
#define WPAD 132       // padded W-tile row (ushorts) to kill epilogue bank conflicts
#define SCAN_B 79      // ceil(N_NODES/256)

typedef __attribute__((ext_vector_type(8))) short short8;
typedef __attribute__((ext_vector_type(4))) float f32x4;

__device__ __forceinline__ float cutoff_f(float d) {
  float c = 0.5f * (__cosf(d * (PI_F / CUTV)) + 1.0f);
  return d < CUTV ? c : 0.0f;
}
__device__ __forceinline__ float silu_f(float x) {
  return x / (1.0f + __expf(-x));
}
// native RNE float->bf16
__device__ __forceinline__ unsigned short bf16bits(float f) {
  union { __hip_bfloat16 b; unsigned short u; } cv;
  cv.b = __float2bfloat16(f);
  return cv.u;
}
__device__ __forceinline__ float bfu_hi(unsigned int bits_in_high) {
  union { unsigned int u; float f; } v; v.u = bits_in_high; return v.f;
}
__device__ __forceinline__ f32x4 mfma16(short8 a, short8 b, f32x4 c) {
  return __builtin_amdgcn_mfma_f32_16x16x32_bf16(a, b, c, 0, 0, 0);
}
// split 8 consecutive floats into hi/lo bf16 fragments
__device__ __forceinline__ void split8(const float* __restrict__ p,
                                       short8& h, short8& l) {
  float4 v0 = *(const float4*)p;
  float4 v1 = *(const float4*)(p + 4);
  float vv[8] = {v0.x, v0.y, v0.z, v0.w, v1.x, v1.y, v1.z, v1.w};
  #pragma unroll
  for (int i = 0; i < 8; ++i) {
    unsigned short hb = bf16bits(vv[i]);
    h[i] = (short)hb;
    l[i] = (short)bf16bits(vv[i] - bfu_hi((unsigned int)hb << 16));
  }
}

// ---------------- CSR build ----------------
__global__ void k_hist(const int* __restrict__ ei, int* __restrict__ deg) {
  int e = blockIdx.x * blockDim.x + threadIdx.x;
  if (e < N_EDGES) atomicAdd(&deg[ei[N_EDGES + e]], 1);
}

// parallel scan: block reduce -> tiny serial scan -> block scan-out
__global__ void k_bsum(const int* __restrict__ deg, int* __restrict__ bsum) {
  __shared__ int sdata[256];
  int b = blockIdx.x, t = threadIdx.x;
  int i = b * 256 + t;
  sdata[t] = (i < N_NODES) ? deg[i] : 0;
  __syncthreads();
  for (int off = 128; off > 0; off >>= 1) {
    if (t < off) sdata[t] += sdata[t + off];
    __syncthreads();
  }
  if (t == 0) bsum[b] = sdata[0];
}

__global__ void k_bscan(const int* __restrict__ bsum, int* __restrict__ boff,
                        int* __restrict__ rowptrN) {
  if (threadIdx.x == 0) {
    int run = 0;
    for (int b = 0; b < SCAN_B; ++b) { boff[b] = run; run += bsum[b]; }
    rowptrN[0] = run;   // = N_EDGES
  }
}

__global__ void k_scanout(const int* __restrict__ deg, const int* __restrict__ boff,
                          int* __restrict__ rowptr, int* __restrict__ cursor) {
  __shared__ int sdata[256];
  int b = blockIdx.x, t = threadIdx.x;
  int i = b * 256 + t;
  int v = (i < N_NODES) ? deg[i] : 0;
  sdata[t] = v;
  __syncthreads();
  for (int off = 1; off < 256; off <<= 1) {
    int add = (t >= off) ? sdata[t - off] : 0;
    __syncthreads();
    sdata[t] += add;
    __syncthreads();
  }
  if (i < N_NODES) {
    int excl = boff[b] + sdata[t] - v;
    rowptr[i] = excl;
    cursor[i] = excl;
  }
}

__global__ void k_scatter(const int* __restrict__ ei, int* __restrict__ cursor,
                          int* __restrict__ eids) {
  int e = blockIdx.x * blockDim.x + threadIdx.x;
  if (e < N_EDGES) {
    int i = ei[N_EDGES + e];
    int p = atomicAdd(&cursor[i], 1);
    eids[p] = e;
  }
}

// ---------------- x0 = emb[z] ----------------
__global__ void k_init(const int* __restrict__ z, const float* __restrict__ emb,
                       float* __restrict__ x) {
  int idx = blockIdx.x * blockDim.x + threadIdx.x;
  if (idx < N_NODES * 32) {
    int n = idx >> 5, c4 = idx & 31;
    float4 v = ((const float4*)emb)[z[n] * 32 + c4];
    ((float4*)x)[n * 32 + c4] = v;
  }
}

// ---------------- attr precompute ----------------
__global__ __launch_bounds__(256)
void k_attr(const int* __restrict__ ei, const float* __restrict__ ew,
            const int* __restrict__ eids, const int* __restrict__ rowptr,
            const float* __restrict__ means, const float* __restrict__ betas,
            unsigned short* __restrict__ attr_fr, float* __restrict__ Csrt,
            float* __restrict__ Cinv, int* __restrict__ srcj) {
  int gid = blockIdx.x * blockDim.x + threadIdx.x;
  int tile = gid >> 9, s = gid & 511;
  int kg = s >> 6, e = s & 63;
  int p = tile * 64 + e;
  int eo = eids[p];
  float d = ew[eo];
  float C = cutoff_f(d);
  float ex = __expf(-d);
  short8 out;
  #pragma unroll
  for (int i = 0; i < 8; ++i) {
    int k = kg * 8 + i;
    float v = 0.0f;
    if (k < RD) {
      float em = ex - means[k];
      v = C * __expf(-betas[k] * em * em);
    }
    out[i] = (short)bf16bits(v);
  }
  *(short8*)(attr_fr + (size_t)gid * 8) = out;
  if (kg == 0) {
    Csrt[p] = C;
    srcj[p] = ei[eo];
    int dn = ei[N_EDGES + eo];
    int dg = rowptr[dn + 1] - rowptr[dn];
    Cinv[p] = C / (float)(dg > 0 ? dg : 1);
  }
}

// ---------------- Pass A: per-edge filter via MFMA, 2-tile pipelined -------
// Processes tile pair (2p, 2p+1) per iteration: shared B-frags, fused
// barriers (5 per pair vs 8), doubled global-load MLP.
template <bool TWO>
__global__ __launch_bounds__(256, 3)
void k_filter(const unsigned short* __restrict__ afr_g,
              const float* __restrict__ scale_e,
              const float* __restrict__ w1g, const float* __restrict__ b1g,
              const float* __restrict__ w2g, const float* __restrict__ bFg,
              unsigned short* __restrict__ Wout) {
  __shared__ unsigned short s_u[2][8192];    // u A-frags per tile (TWO)
  __shared__ unsigned short s_w[64 * WPAD];  // W staging (shared sequentially)
  int t = threadIdx.x;
  int wv = t >> 6, lane = t & 63;
  int c = lane & 15, g = lane >> 4;

  short8 B1[2][2];
  #pragma unroll
  for (int ntl = 0; ntl < 2; ++ntl) {
    int col = (2 * wv + ntl) * 16 + c;
    #pragma unroll
    for (int kt = 0; kt < 2; ++kt) {
      short8 v;
      #pragma unroll
      for (int i = 0; i < 8; ++i) {
        int k = 32 * kt + 8 * g + i;
        v[i] = (k < RD) ? (short)bf16bits(w1g[k * HD + col]) : (short)0;
      }
      B1[ntl][kt] = v;
    }
  }
  short8 B2[2][4];
  if (TWO) {
    #pragma unroll
    for (int ntl = 0; ntl < 2; ++ntl) {
      int col = (2 * wv + ntl) * 16 + c;
      #pragma unroll
      for (int kt = 0; kt < 4; ++kt) {
        short8 v;
        #pragma unroll
        for (int i = 0; i < 8; ++i) {
          int k = 32 * kt + 8 * g + i;
          v[i] = (short)bf16bits(w2g[k * HD + col]);
        }
        B2[ntl][kt] = v;
      }
    }
  }
  float b1v[2], bFv[2];
  #pragma unroll
  for (int ntl = 0; ntl < 2; ++ntl) {
    int col = (2 * wv + ntl) * 16 + c;
    b1v[ntl] = TWO ? b1g[col] : 0.0f;
    bFv[ntl] = bFg[col];
  }

  for (int pair = blockIdx.x; pair < NTILES / 2; pair += gridDim.x) {
    f32x4 acc2[2][4][2];
    #pragma unroll
    for (int hf = 0; hf < 2; ++hf)
      #pragma unroll
      for (int mt = 0; mt < 4; ++mt) {
        acc2[hf][mt][0] = (f32x4){0.f, 0.f, 0.f, 0.f};
        acc2[hf][mt][1] = (f32x4){0.f, 0.f, 0.f, 0.f};
      }
    // GEMM1 both tiles (16 independent global A-frag loads in flight)
    #pragma unroll
    for (int kt = 0; kt < 2; ++kt) {
      #pragma unroll
      for (int mt = 0; mt < 4; ++mt) {
        size_t off = ((size_t)((4 * kt + g) * 64 + (16 * mt + c))) * 8;
        #pragma unroll
        for (int hf = 0; hf < 2; ++hf) {
          const unsigned short* afr = afr_g + (size_t)(2 * pair + hf) * 4096;
          short8 a = *(const short8*)(afr + off);
          acc2[hf][mt][0] = mfma16(a, B1[0][kt], acc2[hf][mt][0]);
          acc2[hf][mt][1] = mfma16(a, B1[1][kt], acc2[hf][mt][1]);
        }
      }
    }
    if (TWO) {
      // silu + stage u for BOTH tiles, then one barrier
      #pragma unroll
      for (int hf = 0; hf < 2; ++hf) {
        #pragma unroll
        for (int mt = 0; mt < 4; ++mt) {
          #pragma unroll
          for (int ntl = 0; ntl < 2; ++ntl) {
            int ch = (2 * wv + ntl) * 16 + c;
            #pragma unroll
            for (int r = 0; r < 4; ++r) {
              int e = 16 * mt + 4 * g + r;
              float v = silu_f(acc2[hf][mt][ntl][r] + b1v[ntl]);
              s_u[hf][((ch >> 3) * 64 + e) * 8 + (ch & 7)] = bf16bits(v);
            }
          }
        }
      }
      __syncthreads();
      #pragma unroll
      for (int hf = 0; hf < 2; ++hf)
        #pragma unroll
        for (int mt = 0; mt < 4; ++mt) {
          acc2[hf][mt][0] = (f32x4){0.f, 0.f, 0.f, 0.f};
          acc2[hf][mt][1] = (f32x4){0.f, 0.f, 0.f, 0.f};
        }
      // GEMM2 both tiles
      #pragma unroll
      for (int kt = 0; kt < 4; ++kt) {
        #pragma unroll
        for (int mt = 0; mt < 4; ++mt) {
          int idx = ((4 * kt + g) * 64 + (16 * mt + c)) * 8;
          #pragma unroll
          for (int hf = 0; hf < 2; ++hf) {
            short8 a = *(const short8*)(s_u[hf] + idx);
            acc2[hf][mt][0] = mfma16(a, B2[0][kt], acc2[hf][mt][0]);
            acc2[hf][mt][1] = mfma16(a, B2[1][kt], acc2[hf][mt][1]);
          }
        }
      }
      __syncthreads();   // GEMM2 reads done; s_u free for next iter, s_w free
    }
    // epilogue + store, tile a then tile b through shared s_w
    #pragma unroll
    for (int hf = 0; hf < 2; ++hf) {
      int tile = 2 * pair + hf;
      #pragma unroll
      for (int mt = 0; mt < 4; ++mt) {
        float Cv[4];
        #pragma unroll
        for (int r = 0; r < 4; ++r) Cv[r] = scale_e[tile * 64 + 16 * mt + 4 * g + r];
        #pragma unroll
        for (int ntl = 0; ntl < 2; ++ntl) {
          int ch = (2 * wv + ntl) * 16 + c;
          #pragma unroll
          for (int r = 0; r < 4; ++r) {
            int e = 16 * mt + 4 * g + r;
            float v = (acc2[hf][mt][ntl][r] + bFv[ntl]) * Cv[r];
            s_w[e * WPAD + ch] = bf16bits(v);
          }
        }
      }
      __syncthreads();
      {
        short8* dst = (short8*)(Wout + (size_t)tile * 8192);
        #pragma unroll
        for (int k2 = 0; k2 < 4; ++k2) {
          int m = t + 256 * k2;
          int e = m >> 4, chunk = m & 15;
          dst[m] = *(const short8*)(s_w + e * WPAD + chunk * 8);
        }
      }
      __syncthreads();
    }
  }
}

// ---------------- Pass B: segment sum (R8 form) ----------------
__global__ __launch_bounds__(256)
void k_segsum(const unsigned short* __restrict__ Wst, const float* __restrict__ h,
              const int* __restrict__ rowptr, const int* __restrict__ srcj,
              float* __restrict__ out) {
  int t = threadIdx.x, wv = t >> 6, lane = t & 63;
  int n = blockIdx.x * 4 + wv;
  if (n >= N_NODES) return;
  int half = lane >> 5;
  int q = lane & 31;
  int beg = rowptr[n], end = rowptr[n + 1];
  float a0 = 0.f, a1 = 0.f, a2 = 0.f, a3 = 0.f;
  #pragma unroll 4
  for (int p = beg + half; p < end; p += 2) {
    int j = srcj[p];
    uint2 wb = *(const uint2*)(Wst + (size_t)p * 128 + 4 * q);
    float4 hv = *(const float4*)(h + (size_t)j * 128 + 4 * q);
    a0 += hv.x * bfu_hi(wb.x << 16);
    a1 += hv.y * bfu_hi(wb.x & 0xffff0000u);
    a2 += hv.z * bfu_hi(wb.y << 16);
    a3 += hv.w * bfu_hi(wb.y & 0xffff0000u);
  }
  a0 += __shfl_xor(a0, 32, 64);
  a1 += __shfl_xor(a1, 32, 64);
  a2 += __shfl_xor(a2, 32, 64);
  a3 += __shfl_xor(a3, 32, 64);
  if (half == 0) {
    *(float4*)(out + (size_t)n * 128 + 4 * q) = make_float4(a0, a1, a2, a3);
  }
}

// ---------------- MFMA node GEMM, split-bf16, 32-row blocks (R8 form) ------
template <int KT, bool HASB, bool SILU, bool ADD>
__global__ __launch_bounds__(512)
void k_nmfma(const float* __restrict__ in1, const float* __restrict__ in2,
             const float* __restrict__ Wg, const float* __restrict__ bias,
             float* __restrict__ out) {
  int t = threadIdx.x;
  int wv = t >> 6, lane = t & 63;
  int c = lane & 15, g = lane >> 4;
  int col = 16 * wv + c;
  int n0 = blockIdx.x * 32;

  short8 Bh[KT], Bl[KT];
  #pragma unroll
  for (int kt = 0; kt < KT; ++kt) {
    short8 h, l;
    #pragma unroll
    for (int i = 0; i < 8; ++i) {
      int k = 32 * kt + 8 * g + i;
      float w = Wg[(size_t)k * HD + col];
      unsigned short hb = bf16bits(w);
      h[i] = (short)hb;
      l[i] = (short)bf16bits(w - bfu_hi((unsigned int)hb << 16));
    }
    Bh[kt] = h; Bl[kt] = l;
  }

  f32x4 acc[2];
  acc[0] = (f32x4){0.f, 0.f, 0.f, 0.f};
  acc[1] = (f32x4){0.f, 0.f, 0.f, 0.f};

  #pragma unroll
  for (int kt = 0; kt < KT; ++kt) {
    const float* in = (KT == 8 && kt >= 4) ? in2 : in1;
    int koff = (kt & 3) * 32 + 8 * g;
    #pragma unroll
    for (int mt = 0; mt < 2; ++mt) {
      int row = n0 + 16 * mt + c;
      int rowc = row < N_NODES ? row : N_NODES - 1;
      short8 ah, al;
      split8(in + (size_t)rowc * HD + koff, ah, al);
      acc[mt] = mfma16(ah, Bh[kt], acc[mt]);
      acc[mt] = mfma16(al, Bh[kt], acc[mt]);
      acc[mt] = mfma16(ah, Bl[kt], acc[mt]);
    }
  }
  __syncthreads();   // all reads done before any in-place store
  float bv = HASB ? bias[col] : 0.0f;
  #pragma unroll
  for (int mt = 0; mt < 2; ++mt) {
    #pragma unroll
    for (int r = 0; r < 4; ++r) {
      int row = n0 + 16 * mt + 4 * g + r;
      if (row < N_NODES) {
        float v = acc[mt][r] + bv;
        if (SILU) v = silu_f(v);
        if (ADD) out[(size_t)row * HD + col] += v;
        else out[(size_t)row * HD + col] = v;
      }
    }
  }
}

// ---------------- fused lin2+silu+lin+residual, 32-row blocks (R8 form) -----
__global__ __launch_bounds__(512)
void k_nmfma2(const float* __restrict__ in1,
              const float* __restrict__ W1, const float* __restrict__ b1,
              const float* __restrict__ W2, const float* __restrict__ b2,
              float* __restrict__ xout) {
  __shared__ unsigned short s_uh[4096];
  __shared__ unsigned short s_ul[4096];
  int t = threadIdx.x;
  int wv = t >> 6, lane = t & 63;
  int c = lane & 15, g = lane >> 4;
  int col = 16 * wv + c;
  int n0 = blockIdx.x * 32;

  short8 B1h[4], B1l[4], B2h[4], B2l[4];
  #pragma unroll
  for (int kt = 0; kt < 4; ++kt) {
    short8 h1, l1, h2, l2;
    #pragma unroll
    for (int i = 0; i < 8; ++i) {
      int k = 32 * kt + 8 * g + i;
      float w = W1[(size_t)k * HD + col];
      unsigned short hb = bf16bits(w);
      h1[i] = (short)hb;
      l1[i] = (short)bf16bits(w - bfu_hi((unsigned int)hb << 16));
      float w2 = W2[(size_t)k * HD + col];
      unsigned short hb2 = bf16bits(w2);
      h2[i] = (short)hb2;
      l2[i] = (short)bf16bits(w2 - bfu_hi((unsigned int)hb2 << 16));
    }
    B1h[kt] = h1; B1l[kt] = l1; B2h[kt] = h2; B2l[kt] = l2;
  }
  float b1v = b1[col], b2v = b2[col];

  f32x4 acc[2];
  acc[0] = (f32x4){0.f, 0.f, 0.f, 0.f};
  acc[1] = (f32x4){0.f, 0.f, 0.f, 0.f};
  #pragma unroll
  for (int kt = 0; kt < 4; ++kt) {
    int koff = kt * 32 + 8 * g;
    #pragma unroll
    for (int mt = 0; mt < 2; ++mt) {
      int row = n0 + 16 * mt + c;
      int rowc = row < N_NODES ? row : N_NODES - 1;
      short8 ah, al;
      split8(in1 + (size_t)rowc * HD + koff, ah, al);
      acc[mt] = mfma16(ah, B1h[kt], acc[mt]);
      acc[mt] = mfma16(al, B1h[kt], acc[mt]);
      acc[mt] = mfma16(ah, B1l[kt], acc[mt]);
    }
  }
  #pragma unroll
  for (int mt = 0; mt < 2; ++mt) {
    #pragma unroll
    for (int r = 0; r < 4; ++r) {
      int e = 16 * mt + 4 * g + r;
      float v = silu_f(acc[mt][r] + b1v);
      unsigned short hb = bf16bits(v);
      unsigned short lb = bf16bits(v - bfu_hi((unsigned int)hb << 16));
      int idx = ((col >> 3) * 32 + e) * 8 + (col & 7);
      s_uh[idx] = hb;
      s_ul[idx] = lb;
    }
  }
  __syncthreads();
  acc[0] = (f32x4){0.f, 0.f, 0.f, 0.f};
  acc[1] = (f32x4){0.f, 0.f, 0.f, 0.f};
  #pragma unroll
  for (int kt = 0; kt < 4; ++kt) {
    #pragma unroll
    for (int mt = 0; mt < 2; ++mt) {
      int idx = ((4 * kt + g) * 32 + (16 * mt + c)) * 8;
      short8 ah = *(const short8*)(s_uh + idx);
      short8 al = *(const short8*)(s_ul + idx);
      acc[mt] = mfma16(ah, B2h[kt], acc[mt]);
      acc[mt] = mfma16(al, B2h[kt], acc[mt]);
      acc[mt] = mfma16(ah, B2l[kt], acc[mt]);
    }
  }
  #pragma unroll
  for (int mt = 0; mt < 2; ++mt) {
    #pragma unroll
    for (int r = 0; r < 4; ++r) {
      int row = n0 + 16 * mt + 4 * g + r;
      if (row < N_NODES) {
        xout[(size_t)row * HD + col] += acc[mt][r] + b2v;
      }
    }
  }
}

extern "C" void kernel_launch(void* const* d_in, const int* in_sizes, int n_in,
                              void* d_out, int out_size, void* d_ws, size_t ws_size,
                              hipStream_t stream) {
  const int* z = (const int*)d_in[0];
  const int* ei = (const int*)d_in[1];
  const float* ew = (const float*)d_in[2];
  const float* emb = (const float*)d_in[3];
  const float* means = (const float*)d_in[4];
  const float* betas = (const float*)d_in[5];
  const float* dp_w = (const float*)d_in[6];
  const float* dp_b = (const float*)d_in[7];
  const float* comb_w = (const float*)d_in[8];
  const float* comb_b = (const float*)d_in[9];
  const float* mlp_w1 = (const float*)d_in[10];
  const float* mlp_b1 = (const float*)d_in[11];
  const float* mlp_w2 = (const float*)d_in[12];
  const float* mlp_b2 = (const float*)d_in[13];
  const float* lin1_w = (const float*)d_in[14];
  const float* lin2_w = (const float*)d_in[15];
  const float* lin2_b = (const float*)d_in[16];
  const float* lin_w = (const float*)d_in[17];
  const float* lin_b = (const float*)d_in[18];
  float* x = (float*)d_out;

  int* rowptr = (int*)d_ws;                         // 20032
  int* deg = rowptr + 20032;                        // 20032
  int* cursor = deg + 20032;                        // 20032
  int* bsum = cursor + 20032;                       // 128
  int* boff = bsum + 128;                           // 128
  int* eids = boff + 128;                           // E
  int* srcj = eids + N_EDGES;                       // E
  float* Csrt = (float*)(srcj + N_EDGES);           // E
  float* Cinv = Csrt + N_EDGES;                     // E
  unsigned short* attr_fr = (unsigned short*)(Cinv + N_EDGES);   // E*64 bf16
  unsigned short* Wst = attr_fr + (size_t)N_EDGES * 64;          // E*128 bf16
  float* hbuf = (float*)(Wst + (size_t)N_EDGES * 128);           // N*128
  float* aggb = hbuf + (size_t)N_NODES * HD;                     // N*128

  hipMemsetAsync(deg, 0, N_NODES * sizeof(int), stream);
  k_hist<<<(N_EDGES + 255) / 256, 256, 0, stream>>>(ei, deg);
  k_bsum<<<SCAN_B, 256, 0, stream>>>(deg, bsum);
  k_bscan<<<1, 64, 0, stream>>>(bsum, boff, rowptr + N_NODES);
  k_scanout<<<SCAN_B, 256, 0, stream>>>(deg, boff, rowptr, cursor);
  k_scatter<<<(N_EDGES + 255) / 256, 256, 0, stream>>>(ei, cursor, eids);
  k_attr<<<NTILES * 2, 256, 0, stream>>>(ei, ew, eids, rowptr, means, betas,
                                         attr_fr, Csrt, Cinv, srcj);
  k_init<<<(N_NODES * 32 + 255) / 256, 256, 0, stream>>>(z, emb, x);

  // dp block: W = (attr@dp_w + dp_b)*C ; agg = segsum(x[j]*W)
  k_filter<false><<<2500, 256, 0, stream>>>(attr_fr, Csrt, dp_w, nullptr,
                                            nullptr, dp_b, Wst);
  k_segsum<<<5000, 256, 0, stream>>>(Wst, x, rowptr, srcj, aggb);
  k_nmfma<8, true, false, false><<<625, 512, 0, stream>>>(x, aggb, comb_w,
                                                          comb_b, x);

  for (int l = 0; l < NL; ++l) {
    k_nmfma<4, false, false, false><<<625, 512, 0, stream>>>(
        x, nullptr, lin1_w + (size_t)l * HD * HD, nullptr, hbuf);
    k_filter<true><<<2500, 256, 0, stream>>>(
        attr_fr, Cinv,
        mlp_w1 + (size_t)l * RD * HD, mlp_b1 + (size_t)l * HD,
        mlp_w2 + (size_t)l * HD * HD, mlp_b2 + (size_t)l * HD, Wst);
    k_segsum<<<5000, 256, 0, stream>>>(Wst, hbuf, rowptr, srcj, aggb);
    k_nmfma2<<<625, 512, 0, stream>>>(
        aggb, lin2_w + (size_t)l * HD * HD, lin2_b + (size_t)l * HD,
        lin_w + (size_t)l * HD * HD, lin_b + (size_t)l * HD, x);
  }
}

// Round 15
// 789.940 us; speedup vs baseline: 1.1367x; 1.1367x over previous
//
#include <hip/hip_runtime.h>
#include <hip/hip_bf16.h>
#include <math.h>

#define N_NODES 20000
#define N_EDGES 320000
#define NTILES  5000   // N_EDGES / 64
#define HD 128
#define RD 50
#define NL 6
#define CUTV 5.0f
#define PI_F 3.14159265358979323846f
#define WPAD 132       // padded W-tile row (ushorts) to kill epilogue bank conflicts
#define SCAN_B 79      // ceil(N_NODES/256)

typedef __attribute__((ext_vector_type(8))) short short8;
typedef __attribute__((ext_vector_type(4))) float f32x4;

__device__ __forceinline__ float cutoff_f(float d) {
  float c = 0.5f * (__cosf(d * (PI_F / CUTV)) + 1.0f);
  return d < CUTV ? c : 0.0f;
}
__device__ __forceinline__ float silu_f(float x) {
  return x / (1.0f + __expf(-x));
}
// native RNE float->bf16
__device__ __forceinline__ unsigned short bf16bits(float f) {
  union { __hip_bfloat16 b; unsigned short u; } cv;
  cv.b = __float2bfloat16(f);
  return cv.u;
}
__device__ __forceinline__ float bfu_hi(unsigned int bits_in_high) {
  union { unsigned int u; float f; } v; v.u = bits_in_high; return v.f;
}
__device__ __forceinline__ f32x4 mfma16(short8 a, short8 b, f32x4 c) {
  return __builtin_amdgcn_mfma_f32_16x16x32_bf16(a, b, c, 0, 0, 0);
}
// split 8 consecutive floats into hi/lo bf16 fragments
__device__ __forceinline__ void split8(const float* __restrict__ p,
                                       short8& h, short8& l) {
  float4 v0 = *(const float4*)p;
  float4 v1 = *(const float4*)(p + 4);
  float vv[8] = {v0.x, v0.y, v0.z, v0.w, v1.x, v1.y, v1.z, v1.w};
  #pragma unroll
  for (int i = 0; i < 8; ++i) {
    unsigned short hb = bf16bits(vv[i]);
    h[i] = (short)hb;
    l[i] = (short)bf16bits(vv[i] - bfu_hi((unsigned int)hb << 16));
  }
}

// ---------------- CSR build ----------------
__global__ void k_hist(const int* __restrict__ ei, int* __restrict__ deg) {
  int e = blockIdx.x * blockDim.x + threadIdx.x;
  if (e < N_EDGES) atomicAdd(&deg[ei[N_EDGES + e]], 1);
}

// parallel scan: block reduce -> tiny serial scan -> block scan-out
__global__ void k_bsum(const int* __restrict__ deg, int* __restrict__ bsum) {
  __shared__ int sdata[256];
  int b = blockIdx.x, t = threadIdx.x;
  int i = b * 256 + t;
  sdata[t] = (i < N_NODES) ? deg[i] : 0;
  __syncthreads();
  for (int off = 128; off > 0; off >>= 1) {
    if (t < off) sdata[t] += sdata[t + off];
    __syncthreads();
  }
  if (t == 0) bsum[b] = sdata[0];
}

__global__ void k_bscan(const int* __restrict__ bsum, int* __restrict__ boff,
                        int* __restrict__ rowptrN) {
  if (threadIdx.x == 0) {
    int run = 0;
    for (int b = 0; b < SCAN_B; ++b) { boff[b] = run; run += bsum[b]; }
    rowptrN[0] = run;   // = N_EDGES
  }
}

__global__ void k_scanout(const int* __restrict__ deg, const int* __restrict__ boff,
                          int* __restrict__ rowptr, int* __restrict__ cursor) {
  __shared__ int sdata[256];
  int b = blockIdx.x, t = threadIdx.x;
  int i = b * 256 + t;
  int v = (i < N_NODES) ? deg[i] : 0;
  sdata[t] = v;
  __syncthreads();
  for (int off = 1; off < 256; off <<= 1) {
    int add = (t >= off) ? sdata[t - off] : 0;
    __syncthreads();
    sdata[t] += add;
    __syncthreads();
  }
  if (i < N_NODES) {
    int excl = boff[b] + sdata[t] - v;
    rowptr[i] = excl;
    cursor[i] = excl;
  }
}

__global__ void k_scatter(const int* __restrict__ ei, int* __restrict__ cursor,
                          int* __restrict__ eids) {
  int e = blockIdx.x * blockDim.x + threadIdx.x;
  if (e < N_EDGES) {
    int i = ei[N_EDGES + e];
    int p = atomicAdd(&cursor[i], 1);
    eids[p] = e;
  }
}

// ---------------- x0 = emb[z] ----------------
__global__ void k_init(const int* __restrict__ z, const float* __restrict__ emb,
                       float* __restrict__ x) {
  int idx = blockIdx.x * blockDim.x + threadIdx.x;
  if (idx < N_NODES * 32) {
    int n = idx >> 5, c4 = idx & 31;
    float4 v = ((const float4*)emb)[z[n] * 32 + c4];
    ((float4*)x)[n * 32 + c4] = v;
  }
}

// ---------------- attr precompute ----------------
__global__ __launch_bounds__(256)
void k_attr(const int* __restrict__ ei, const float* __restrict__ ew,
            const int* __restrict__ eids, const int* __restrict__ rowptr,
            const float* __restrict__ means, const float* __restrict__ betas,
            unsigned short* __restrict__ attr_fr, float* __restrict__ Csrt,
            float* __restrict__ Cinv, int* __restrict__ srcj) {
  int gid = blockIdx.x * blockDim.x + threadIdx.x;
  int tile = gid >> 9, s = gid & 511;
  int kg = s >> 6, e = s & 63;
  int p = tile * 64 + e;
  int eo = eids[p];
  float d = ew[eo];
  float C = cutoff_f(d);
  float ex = __expf(-d);
  short8 out;
  #pragma unroll
  for (int i = 0; i < 8; ++i) {
    int k = kg * 8 + i;
    float v = 0.0f;
    if (k < RD) {
      float em = ex - means[k];
      v = C * __expf(-betas[k] * em * em);
    }
    out[i] = (short)bf16bits(v);
  }
  *(short8*)(attr_fr + (size_t)gid * 8) = out;
  if (kg == 0) {
    Csrt[p] = C;
    srcj[p] = ei[eo];
    int dn = ei[N_EDGES + eo];
    int dg = rowptr[dn + 1] - rowptr[dn];
    Cinv[p] = C / (float)(dg > 0 ? dg : 1);
  }
}

// ---------------- Pass A: per-edge filter via MFMA (R13 proven form) -------
template <bool TWO>
__global__ __launch_bounds__(256, 4)
void k_filter(const unsigned short* __restrict__ afr_g,
              const float* __restrict__ scale_e,
              const float* __restrict__ w1g, const float* __restrict__ b1g,
              const float* __restrict__ w2g, const float* __restrict__ bFg,
              unsigned short* __restrict__ Wout) {
  __shared__ unsigned short s_u[64 * WPAD];
  int t = threadIdx.x;
  int wv = t >> 6, lane = t & 63;
  int c = lane & 15, g = lane >> 4;

  short8 B1[2][2];
  #pragma unroll
  for (int ntl = 0; ntl < 2; ++ntl) {
    int col = (2 * wv + ntl) * 16 + c;
    #pragma unroll
    for (int kt = 0; kt < 2; ++kt) {
      short8 v;
      #pragma unroll
      for (int i = 0; i < 8; ++i) {
        int k = 32 * kt + 8 * g + i;
        v[i] = (k < RD) ? (short)bf16bits(w1g[k * HD + col]) : (short)0;
      }
      B1[ntl][kt] = v;
    }
  }
  short8 B2[2][4];
  if (TWO) {
    #pragma unroll
    for (int ntl = 0; ntl < 2; ++ntl) {
      int col = (2 * wv + ntl) * 16 + c;
      #pragma unroll
      for (int kt = 0; kt < 4; ++kt) {
        short8 v;
        #pragma unroll
        for (int i = 0; i < 8; ++i) {
          int k = 32 * kt + 8 * g + i;
          v[i] = (short)bf16bits(w2g[k * HD + col]);
        }
        B2[ntl][kt] = v;
      }
    }
  }
  float b1v[2], bFv[2];
  #pragma unroll
  for (int ntl = 0; ntl < 2; ++ntl) {
    int col = (2 * wv + ntl) * 16 + c;
    b1v[ntl] = TWO ? b1g[col] : 0.0f;
    bFv[ntl] = bFg[col];
  }

  for (int tile = blockIdx.x; tile < NTILES; tile += gridDim.x) {
    const unsigned short* afr = afr_g + (size_t)tile * 4096;
    f32x4 acc[4][2];
    #pragma unroll
    for (int mt = 0; mt < 4; ++mt) {
      acc[mt][0] = (f32x4){0.f, 0.f, 0.f, 0.f};
      acc[mt][1] = (f32x4){0.f, 0.f, 0.f, 0.f};
    }
    #pragma unroll
    for (int kt = 0; kt < 2; ++kt) {
      #pragma unroll
      for (int mt = 0; mt < 4; ++mt) {
        short8 a = *(const short8*)(afr + ((size_t)((4 * kt + g) * 64 + (16 * mt + c))) * 8);
        acc[mt][0] = mfma16(a, B1[0][kt], acc[mt][0]);
        acc[mt][1] = mfma16(a, B1[1][kt], acc[mt][1]);
      }
    }
    if (TWO) {
      #pragma unroll
      for (int mt = 0; mt < 4; ++mt) {
        #pragma unroll
        for (int ntl = 0; ntl < 2; ++ntl) {
          int ch = (2 * wv + ntl) * 16 + c;
          #pragma unroll
          for (int r = 0; r < 4; ++r) {
            int e = 16 * mt + 4 * g + r;
            float v = silu_f(acc[mt][ntl][r] + b1v[ntl]);
            s_u[((ch >> 3) * 64 + e) * 8 + (ch & 7)] = bf16bits(v);
          }
        }
      }
      __syncthreads();
      #pragma unroll
      for (int mt = 0; mt < 4; ++mt) {
        acc[mt][0] = (f32x4){0.f, 0.f, 0.f, 0.f};
        acc[mt][1] = (f32x4){0.f, 0.f, 0.f, 0.f};
      }
      #pragma unroll
      for (int kt = 0; kt < 4; ++kt) {
        #pragma unroll
        for (int mt = 0; mt < 4; ++mt) {
          short8 a = *(const short8*)(s_u + ((4 * kt + g) * 64 + (16 * mt + c)) * 8);
          acc[mt][0] = mfma16(a, B2[0][kt], acc[mt][0]);
          acc[mt][1] = mfma16(a, B2[1][kt], acc[mt][1]);
        }
      }
      __syncthreads();
    }
    #pragma unroll
    for (int mt = 0; mt < 4; ++mt) {
      float Cv[4];
      #pragma unroll
      for (int r = 0; r < 4; ++r) Cv[r] = scale_e[tile * 64 + 16 * mt + 4 * g + r];
      #pragma unroll
      for (int ntl = 0; ntl < 2; ++ntl) {
        int ch = (2 * wv + ntl) * 16 + c;
        #pragma unroll
        for (int r = 0; r < 4; ++r) {
          int e = 16 * mt + 4 * g + r;
          float v = (acc[mt][ntl][r] + bFv[ntl]) * Cv[r];
          s_u[e * WPAD + ch] = bf16bits(v);
        }
      }
    }
    __syncthreads();
    {
      short8* dst = (short8*)(Wout + (size_t)tile * 8192);
      #pragma unroll
      for (int k2 = 0; k2 < 4; ++k2) {
        int m = t + 256 * k2;
        int e = m >> 4, chunk = m & 15;
        dst[m] = *(const short8*)(s_u + e * WPAD + chunk * 8);
      }
    }
    __syncthreads();
  }
}

// ---------------- Pass B: segment sum (R8 form) ----------------
__global__ __launch_bounds__(256)
void k_segsum(const unsigned short* __restrict__ Wst, const float* __restrict__ h,
              const int* __restrict__ rowptr, const int* __restrict__ srcj,
              float* __restrict__ out) {
  int t = threadIdx.x, wv = t >> 6, lane = t & 63;
  int n = blockIdx.x * 4 + wv;
  if (n >= N_NODES) return;
  int half = lane >> 5;
  int q = lane & 31;
  int beg = rowptr[n], end = rowptr[n + 1];
  float a0 = 0.f, a1 = 0.f, a2 = 0.f, a3 = 0.f;
  #pragma unroll 4
  for (int p = beg + half; p < end; p += 2) {
    int j = srcj[p];
    uint2 wb = *(const uint2*)(Wst + (size_t)p * 128 + 4 * q);
    float4 hv = *(const float4*)(h + (size_t)j * 128 + 4 * q);
    a0 += hv.x * bfu_hi(wb.x << 16);
    a1 += hv.y * bfu_hi(wb.x & 0xffff0000u);
    a2 += hv.z * bfu_hi(wb.y << 16);
    a3 += hv.w * bfu_hi(wb.y & 0xffff0000u);
  }
  a0 += __shfl_xor(a0, 32, 64);
  a1 += __shfl_xor(a1, 32, 64);
  a2 += __shfl_xor(a2, 32, 64);
  a3 += __shfl_xor(a3, 32, 64);
  if (half == 0) {
    *(float4*)(out + (size_t)n * 128 + 4 * q) = make_float4(a0, a1, a2, a3);
  }
}

// ---------------- MFMA node GEMM, split-bf16, 32-row blocks ----------------
// LIN1: after writing out, also compute hout = out_block @ W3 (no bias) via
// the u-staging D-frag->A-frag relayout (same arithmetic as standalone lin1).
template <int KT, bool HASB, bool SILU, bool ADD, bool LIN1>
__global__ __launch_bounds__(512)
void k_nmfma(const float* __restrict__ in1, const float* __restrict__ in2,
             const float* __restrict__ Wg, const float* __restrict__ bias,
             float* __restrict__ out,
             const float* __restrict__ W3, float* __restrict__ hout) {
  __shared__ unsigned short s_h[LIN1 ? 4096 : 8];
  __shared__ unsigned short s_l[LIN1 ? 4096 : 8];
  int t = threadIdx.x;
  int wv = t >> 6, lane = t & 63;
  int c = lane & 15, g = lane >> 4;
  int col = 16 * wv + c;
  int n0 = blockIdx.x * 32;

  short8 Bh[KT], Bl[KT];
  #pragma unroll
  for (int kt = 0; kt < KT; ++kt) {
    short8 h, l;
    #pragma unroll
    for (int i = 0; i < 8; ++i) {
      int k = 32 * kt + 8 * g + i;
      float w = Wg[(size_t)k * HD + col];
      unsigned short hb = bf16bits(w);
      h[i] = (short)hb;
      l[i] = (short)bf16bits(w - bfu_hi((unsigned int)hb << 16));
    }
    Bh[kt] = h; Bl[kt] = l;
  }

  f32x4 acc[2];
  acc[0] = (f32x4){0.f, 0.f, 0.f, 0.f};
  acc[1] = (f32x4){0.f, 0.f, 0.f, 0.f};

  #pragma unroll
  for (int kt = 0; kt < KT; ++kt) {
    const float* in = (KT == 8 && kt >= 4) ? in2 : in1;
    int koff = (kt & 3) * 32 + 8 * g;
    #pragma unroll
    for (int mt = 0; mt < 2; ++mt) {
      int row = n0 + 16 * mt + c;
      int rowc = row < N_NODES ? row : N_NODES - 1;
      short8 ah, al;
      split8(in + (size_t)rowc * HD + koff, ah, al);
      acc[mt] = mfma16(ah, Bh[kt], acc[mt]);
      acc[mt] = mfma16(al, Bh[kt], acc[mt]);
      acc[mt] = mfma16(ah, Bl[kt], acc[mt]);
    }
  }
  __syncthreads();   // all reads done before any in-place store
  float bv = HASB ? bias[col] : 0.0f;
  #pragma unroll
  for (int mt = 0; mt < 2; ++mt) {
    #pragma unroll
    for (int r = 0; r < 4; ++r) {
      int row = n0 + 16 * mt + 4 * g + r;
      if (row < N_NODES) {
        float v = acc[mt][r] + bv;
        if (SILU) v = silu_f(v);
        if (ADD) v += out[(size_t)row * HD + col];
        out[(size_t)row * HD + col] = v;
        if (LIN1) {
          int e = 16 * mt + 4 * g + r;
          unsigned short hb = bf16bits(v);
          unsigned short lb = bf16bits(v - bfu_hi((unsigned int)hb << 16));
          int idx = ((col >> 3) * 32 + e) * 8 + (col & 7);
          s_h[idx] = hb;
          s_l[idx] = lb;
        }
      }
    }
  }
  if (LIN1) {
    __syncthreads();
    short8 B3h[4], B3l[4];
    #pragma unroll
    for (int kt = 0; kt < 4; ++kt) {
      short8 h, l;
      #pragma unroll
      for (int i = 0; i < 8; ++i) {
        int k = 32 * kt + 8 * g + i;
        float w = W3[(size_t)k * HD + col];
        unsigned short hb = bf16bits(w);
        h[i] = (short)hb;
        l[i] = (short)bf16bits(w - bfu_hi((unsigned int)hb << 16));
      }
      B3h[kt] = h; B3l[kt] = l;
    }
    f32x4 acc3[2];
    acc3[0] = (f32x4){0.f, 0.f, 0.f, 0.f};
    acc3[1] = (f32x4){0.f, 0.f, 0.f, 0.f};
    #pragma unroll
    for (int kt = 0; kt < 4; ++kt) {
      #pragma unroll
      for (int mt = 0; mt < 2; ++mt) {
        int idx = ((4 * kt + g) * 32 + (16 * mt + c)) * 8;
        short8 ah = *(const short8*)(s_h + idx);
        short8 al = *(const short8*)(s_l + idx);
        acc3[mt] = mfma16(ah, B3h[kt], acc3[mt]);
        acc3[mt] = mfma16(al, B3h[kt], acc3[mt]);
        acc3[mt] = mfma16(ah, B3l[kt], acc3[mt]);
      }
    }
    #pragma unroll
    for (int mt = 0; mt < 2; ++mt) {
      #pragma unroll
      for (int r = 0; r < 4; ++r) {
        int row = n0 + 16 * mt + 4 * g + r;
        if (row < N_NODES) hout[(size_t)row * HD + col] = acc3[mt][r];
      }
    }
  }
}

// ---------------- fused lin2+silu+lin+residual (+ next-layer lin1) ---------
template <bool LIN1>
__global__ __launch_bounds__(512)
void k_nmfma2(const float* __restrict__ in1,
              const float* __restrict__ W1, const float* __restrict__ b1,
              const float* __restrict__ W2, const float* __restrict__ b2,
              float* __restrict__ xout,
              const float* __restrict__ W3, float* __restrict__ hout) {
  __shared__ unsigned short s_uh[4096];
  __shared__ unsigned short s_ul[4096];
  int t = threadIdx.x;
  int wv = t >> 6, lane = t & 63;
  int c = lane & 15, g = lane >> 4;
  int col = 16 * wv + c;
  int n0 = blockIdx.x * 32;

  short8 B1h[4], B1l[4], B2h[4], B2l[4];
  #pragma unroll
  for (int kt = 0; kt < 4; ++kt) {
    short8 h1, l1, h2, l2;
    #pragma unroll
    for (int i = 0; i < 8; ++i) {
      int k = 32 * kt + 8 * g + i;
      float w = W1[(size_t)k * HD + col];
      unsigned short hb = bf16bits(w);
      h1[i] = (short)hb;
      l1[i] = (short)bf16bits(w - bfu_hi((unsigned int)hb << 16));
      float w2 = W2[(size_t)k * HD + col];
      unsigned short hb2 = bf16bits(w2);
      h2[i] = (short)hb2;
      l2[i] = (short)bf16bits(w2 - bfu_hi((unsigned int)hb2 << 16));
    }
    B1h[kt] = h1; B1l[kt] = l1; B2h[kt] = h2; B2l[kt] = l2;
  }
  float b1v = b1[col], b2v = b2[col];

  f32x4 acc[2];
  acc[0] = (f32x4){0.f, 0.f, 0.f, 0.f};
  acc[1] = (f32x4){0.f, 0.f, 0.f, 0.f};
  #pragma unroll
  for (int kt = 0; kt < 4; ++kt) {
    int koff = kt * 32 + 8 * g;
    #pragma unroll
    for (int mt = 0; mt < 2; ++mt) {
      int row = n0 + 16 * mt + c;
      int rowc = row < N_NODES ? row : N_NODES - 1;
      short8 ah, al;
      split8(in1 + (size_t)rowc * HD + koff, ah, al);
      acc[mt] = mfma16(ah, B1h[kt], acc[mt]);
      acc[mt] = mfma16(al, B1h[kt], acc[mt]);
      acc[mt] = mfma16(ah, B1l[kt], acc[mt]);
    }
  }
  #pragma unroll
  for (int mt = 0; mt < 2; ++mt) {
    #pragma unroll
    for (int r = 0; r < 4; ++r) {
      int e = 16 * mt + 4 * g + r;
      float v = silu_f(acc[mt][r] + b1v);
      unsigned short hb = bf16bits(v);
      unsigned short lb = bf16bits(v - bfu_hi((unsigned int)hb << 16));
      int idx = ((col >> 3) * 32 + e) * 8 + (col & 7);
      s_uh[idx] = hb;
      s_ul[idx] = lb;
    }
  }
  __syncthreads();
  acc[0] = (f32x4){0.f, 0.f, 0.f, 0.f};
  acc[1] = (f32x4){0.f, 0.f, 0.f, 0.f};
  #pragma unroll
  for (int kt = 0; kt < 4; ++kt) {
    #pragma unroll
    for (int mt = 0; mt < 2; ++mt) {
      int idx = ((4 * kt + g) * 32 + (16 * mt + c)) * 8;
      short8 ah = *(const short8*)(s_uh + idx);
      short8 al = *(const short8*)(s_ul + idx);
      acc[mt] = mfma16(ah, B2h[kt], acc[mt]);
      acc[mt] = mfma16(al, B2h[kt], acc[mt]);
      acc[mt] = mfma16(ah, B2l[kt], acc[mt]);
    }
  }
  __syncthreads();   // GEMM2 reads of s_u done; buffers free for x re-stage
  #pragma unroll
  for (int mt = 0; mt < 2; ++mt) {
    #pragma unroll
    for (int r = 0; r < 4; ++r) {
      int row = n0 + 16 * mt + 4 * g + r;
      if (row < N_NODES) {
        float v = xout[(size_t)row * HD + col] + acc[mt][r] + b2v;
        xout[(size_t)row * HD + col] = v;
        if (LIN1) {
          int e = 16 * mt + 4 * g + r;
          unsigned short hb = bf16bits(v);
          unsigned short lb = bf16bits(v - bfu_hi((unsigned int)hb << 16));
          int idx = ((col >> 3) * 32 + e) * 8 + (col & 7);
          s_uh[idx] = hb;
          s_ul[idx] = lb;
        }
      }
    }
  }
  if (LIN1) {
    __syncthreads();
    short8 B3h[4], B3l[4];
    #pragma unroll
    for (int kt = 0; kt < 4; ++kt) {
      short8 h, l;
      #pragma unroll
      for (int i = 0; i < 8; ++i) {
        int k = 32 * kt + 8 * g + i;
        float w = W3[(size_t)k * HD + col];
        unsigned short hb = bf16bits(w);
        h[i] = (short)hb;
        l[i] = (short)bf16bits(w - bfu_hi((unsigned int)hb << 16));
      }
      B3h[kt] = h; B3l[kt] = l;
    }
    f32x4 acc3[2];
    acc3[0] = (f32x4){0.f, 0.f, 0.f, 0.f};
    acc3[1] = (f32x4){0.f, 0.f, 0.f, 0.f};
    #pragma unroll
    for (int kt = 0; kt < 4; ++kt) {
      #pragma unroll
      for (int mt = 0; mt < 2; ++mt) {
        int idx = ((4 * kt + g) * 32 + (16 * mt + c)) * 8;
        short8 ah = *(const short8*)(s_uh + idx);
        short8 al = *(const short8*)(s_ul + idx);
        acc3[mt] = mfma16(ah, B3h[kt], acc3[mt]);
        acc3[mt] = mfma16(al, B3h[kt], acc3[mt]);
        acc3[mt] = mfma16(ah, B3l[kt], acc3[mt]);
      }
    }
    #pragma unroll
    for (int mt = 0; mt < 2; ++mt) {
      #pragma unroll
      for (int r = 0; r < 4; ++r) {
        int row = n0 + 16 * mt + 4 * g + r;
        if (row < N_NODES) hout[(size_t)row * HD + col] = acc3[mt][r];
      }
    }
  }
}

extern "C" void kernel_launch(void* const* d_in, const int* in_sizes, int n_in,
                              void* d_out, int out_size, void* d_ws, size_t ws_size,
                              hipStream_t stream) {
  const int* z = (const int*)d_in[0];
  const int* ei = (const int*)d_in[1];
  const float* ew = (const float*)d_in[2];
  const float* emb = (const float*)d_in[3];
  const float* means = (const float*)d_in[4];
  const float* betas = (const float*)d_in[5];
  const float* dp_w = (const float*)d_in[6];
  const float* dp_b = (const float*)d_in[7];
  const float* comb_w = (const float*)d_in[8];
  const float* comb_b = (const float*)d_in[9];
  const float* mlp_w1 = (const float*)d_in[10];
  const float* mlp_b1 = (const float*)d_in[11];
  const float* mlp_w2 = (const float*)d_in[12];
  const float* mlp_b2 = (const float*)d_in[13];
  const float* lin1_w = (const float*)d_in[14];
  const float* lin2_w = (const float*)d_in[15];
  const float* lin2_b = (const float*)d_in[16];
  const float* lin_w = (const float*)d_in[17];
  const float* lin_b = (const float*)d_in[18];
  float* x = (float*)d_out;

  int* rowptr = (int*)d_ws;                         // 20032
  int* deg = rowptr + 20032;                        // 20032
  int* cursor = deg + 20032;                        // 20032
  int* bsum = cursor + 20032;                       // 128
  int* boff = bsum + 128;                           // 128
  int* eids = boff + 128;                           // E
  int* srcj = eids + N_EDGES;                       // E
  float* Csrt = (float*)(srcj + N_EDGES);           // E
  float* Cinv = Csrt + N_EDGES;                     // E
  unsigned short* attr_fr = (unsigned short*)(Cinv + N_EDGES);   // E*64 bf16
  unsigned short* Wst = attr_fr + (size_t)N_EDGES * 64;          // E*128 bf16
  float* hbuf = (float*)(Wst + (size_t)N_EDGES * 128);           // N*128
  float* aggb = hbuf + (size_t)N_NODES * HD;                     // N*128

  hipMemsetAsync(deg, 0, N_NODES * sizeof(int), stream);
  k_hist<<<(N_EDGES + 255) / 256, 256, 0, stream>>>(ei, deg);
  k_bsum<<<SCAN_B, 256, 0, stream>>>(deg, bsum);
  k_bscan<<<1, 64, 0, stream>>>(bsum, boff, rowptr + N_NODES);
  k_scanout<<<SCAN_B, 256, 0, stream>>>(deg, boff, rowptr, cursor);
  k_scatter<<<(N_EDGES + 255) / 256, 256, 0, stream>>>(ei, cursor, eids);
  k_attr<<<NTILES * 2, 256, 0, stream>>>(ei, ew, eids, rowptr, means, betas,
                                         attr_fr, Csrt, Cinv, srcj);
  k_init<<<(N_NODES * 32 + 255) / 256, 256, 0, stream>>>(z, emb, x);

  // dp block: W = (attr@dp_w + dp_b)*C ; agg = segsum(x[j]*W)
  k_filter<false><<<2500, 256, 0, stream>>>(attr_fr, Csrt, dp_w, nullptr,
                                            nullptr, dp_b, Wst);
  k_segsum<<<5000, 256, 0, stream>>>(Wst, x, rowptr, srcj, aggb);
  // comb (+ fused lin1 of layer 0)
  k_nmfma<8, true, false, false, true><<<625, 512, 0, stream>>>(
      x, aggb, comb_w, comb_b, x, lin1_w, hbuf);

  for (int l = 0; l < NL; ++l) {
    k_filter<true><<<2500, 256, 0, stream>>>(
        attr_fr, Cinv,
        mlp_w1 + (size_t)l * RD * HD, mlp_b1 + (size_t)l * HD,
        mlp_w2 + (size_t)l * HD * HD, mlp_b2 + (size_t)l * HD, Wst);
    k_segsum<<<5000, 256, 0, stream>>>(Wst, hbuf, rowptr, srcj, aggb);
    if (l < NL - 1) {
      k_nmfma2<true><<<625, 512, 0, stream>>>(
          aggb, lin2_w + (size_t)l * HD * HD, lin2_b + (size_t)l * HD,
          lin_w + (size_t)l * HD * HD, lin_b + (size_t)l * HD, x,
          lin1_w + (size_t)(l + 1) * HD * HD, hbuf);
    } else {
      k_nmfma2<false><<<625, 512, 0, stream>>>(
          aggb, lin2_w + (size_t)l * HD * HD, lin2_b + (size_t)l * HD,
          lin_w + (size_t)l * HD * HD, lin_b + (size_t)l * HD, x,
          nullptr, nullptr);
    }
  }
}

// Round 16
// 754.068 us; speedup vs baseline: 1.1907x; 1.0476x over previous
//
#include <hip/hip_runtime.h>
#include <hip/hip_bf16.h>
#include <math.h>

#define N_NODES 20000
#define N_EDGES 320000
#define NTILES  5000   // N_EDGES / 64
#define HD 128
#define RD 50
#define NL 6
#define CUTV 5.0f
#define PI_F 3.14159265358979323846f
#define WPAD 132       // padded W-tile row (ushorts) to kill epilogue bank conflicts
#define SCAN_B 79      // ceil(N_NODES/256)

typedef __attribute__((ext_vector_type(8))) short short8;
typedef __attribute__((ext_vector_type(4))) float f32x4;

__device__ __forceinline__ float cutoff_f(float d) {
  float c = 0.5f * (__cosf(d * (PI_F / CUTV)) + 1.0f);
  return d < CUTV ? c : 0.0f;
}
// silu via fast v_rcp (x/(1+e^-x) div sequence is ~8 VALU ops; rcp+mul is 2)
__device__ __forceinline__ float silu_f(float x) {
  return x * __builtin_amdgcn_rcpf(1.0f + __expf(-x));
}
// native RNE float->bf16
__device__ __forceinline__ unsigned short bf16bits(float f) {
  union { __hip_bfloat16 b; unsigned short u; } cv;
  cv.b = __float2bfloat16(f);
  return cv.u;
}
__device__ __forceinline__ float bfu_hi(unsigned int bits_in_high) {
  union { unsigned int u; float f; } v; v.u = bits_in_high; return v.f;
}
__device__ __forceinline__ f32x4 mfma16(short8 a, short8 b, f32x4 c) {
  return __builtin_amdgcn_mfma_f32_16x16x32_bf16(a, b, c, 0, 0, 0);
}
// split 8 consecutive floats into hi/lo bf16 fragments
__device__ __forceinline__ void split8(const float* __restrict__ p,
                                       short8& h, short8& l) {
  float4 v0 = *(const float4*)p;
  float4 v1 = *(const float4*)(p + 4);
  float vv[8] = {v0.x, v0.y, v0.z, v0.w, v1.x, v1.y, v1.z, v1.w};
  #pragma unroll
  for (int i = 0; i < 8; ++i) {
    unsigned short hb = bf16bits(vv[i]);
    h[i] = (short)hb;
    l[i] = (short)bf16bits(vv[i] - bfu_hi((unsigned int)hb << 16));
  }
}

// ---------------- CSR build ----------------
__global__ void k_hist(const int* __restrict__ ei, int* __restrict__ deg) {
  int e = blockIdx.x * blockDim.x + threadIdx.x;
  if (e < N_EDGES) atomicAdd(&deg[ei[N_EDGES + e]], 1);
}

// parallel scan: block reduce -> tiny serial scan -> block scan-out
__global__ void k_bsum(const int* __restrict__ deg, int* __restrict__ bsum) {
  __shared__ int sdata[256];
  int b = blockIdx.x, t = threadIdx.x;
  int i = b * 256 + t;
  sdata[t] = (i < N_NODES) ? deg[i] : 0;
  __syncthreads();
  for (int off = 128; off > 0; off >>= 1) {
    if (t < off) sdata[t] += sdata[t + off];
    __syncthreads();
  }
  if (t == 0) bsum[b] = sdata[0];
}

__global__ void k_bscan(const int* __restrict__ bsum, int* __restrict__ boff,
                        int* __restrict__ rowptrN) {
  if (threadIdx.x == 0) {
    int run = 0;
    for (int b = 0; b < SCAN_B; ++b) { boff[b] = run; run += bsum[b]; }
    rowptrN[0] = run;   // = N_EDGES
  }
}

__global__ void k_scanout(const int* __restrict__ deg, const int* __restrict__ boff,
                          int* __restrict__ rowptr, int* __restrict__ cursor) {
  __shared__ int sdata[256];
  int b = blockIdx.x, t = threadIdx.x;
  int i = b * 256 + t;
  int v = (i < N_NODES) ? deg[i] : 0;
  sdata[t] = v;
  __syncthreads();
  for (int off = 1; off < 256; off <<= 1) {
    int add = (t >= off) ? sdata[t - off] : 0;
    __syncthreads();
    sdata[t] += add;
    __syncthreads();
  }
  if (i < N_NODES) {
    int excl = boff[b] + sdata[t] - v;
    rowptr[i] = excl;
    cursor[i] = excl;
  }
}

__global__ void k_scatter(const int* __restrict__ ei, int* __restrict__ cursor,
                          int* __restrict__ eids) {
  int e = blockIdx.x * blockDim.x + threadIdx.x;
  if (e < N_EDGES) {
    int i = ei[N_EDGES + e];
    int p = atomicAdd(&cursor[i], 1);
    eids[p] = e;
  }
}

// ---------------- x0 = emb[z] ----------------
__global__ void k_init(const int* __restrict__ z, const float* __restrict__ emb,
                       float* __restrict__ x) {
  int idx = blockIdx.x * blockDim.x + threadIdx.x;
  if (idx < N_NODES * 32) {
    int n = idx >> 5, c4 = idx & 31;
    float4 v = ((const float4*)emb)[z[n] * 32 + c4];
    ((float4*)x)[n * 32 + c4] = v;
  }
}

// ---------------- attr precompute ----------------
__global__ __launch_bounds__(256)
void k_attr(const int* __restrict__ ei, const float* __restrict__ ew,
            const int* __restrict__ eids, const int* __restrict__ rowptr,
            const float* __restrict__ means, const float* __restrict__ betas,
            unsigned short* __restrict__ attr_fr, float* __restrict__ Csrt,
            float* __restrict__ Cinv, int* __restrict__ srcj) {
  int gid = blockIdx.x * blockDim.x + threadIdx.x;
  int tile = gid >> 9, s = gid & 511;
  int kg = s >> 6, e = s & 63;
  int p = tile * 64 + e;
  int eo = eids[p];
  float d = ew[eo];
  float C = cutoff_f(d);
  float ex = __expf(-d);
  short8 out;
  #pragma unroll
  for (int i = 0; i < 8; ++i) {
    int k = kg * 8 + i;
    float v = 0.0f;
    if (k < RD) {
      float em = ex - means[k];
      v = C * __expf(-betas[k] * em * em);
    }
    out[i] = (short)bf16bits(v);
  }
  *(short8*)(attr_fr + (size_t)gid * 8) = out;
  if (kg == 0) {
    Csrt[p] = C;
    srcj[p] = ei[eo];
    int dn = ei[N_EDGES + eo];
    int dg = rowptr[dn + 1] - rowptr[dn];
    Cinv[p] = C / (float)(dg > 0 ? dg : 1);
  }
}

// ---------------- Pass A: per-edge filter via MFMA (R13 proven form) -------
template <bool TWO>
__global__ __launch_bounds__(256, 4)
void k_filter(const unsigned short* __restrict__ afr_g,
              const float* __restrict__ scale_e,
              const float* __restrict__ w1g, const float* __restrict__ b1g,
              const float* __restrict__ w2g, const float* __restrict__ bFg,
              unsigned short* __restrict__ Wout) {
  __shared__ unsigned short s_u[64 * WPAD];
  int t = threadIdx.x;
  int wv = t >> 6, lane = t & 63;
  int c = lane & 15, g = lane >> 4;

  short8 B1[2][2];
  #pragma unroll
  for (int ntl = 0; ntl < 2; ++ntl) {
    int col = (2 * wv + ntl) * 16 + c;
    #pragma unroll
    for (int kt = 0; kt < 2; ++kt) {
      short8 v;
      #pragma unroll
      for (int i = 0; i < 8; ++i) {
        int k = 32 * kt + 8 * g + i;
        v[i] = (k < RD) ? (short)bf16bits(w1g[k * HD + col]) : (short)0;
      }
      B1[ntl][kt] = v;
    }
  }
  short8 B2[2][4];
  if (TWO) {
    #pragma unroll
    for (int ntl = 0; ntl < 2; ++ntl) {
      int col = (2 * wv + ntl) * 16 + c;
      #pragma unroll
      for (int kt = 0; kt < 4; ++kt) {
        short8 v;
        #pragma unroll
        for (int i = 0; i < 8; ++i) {
          int k = 32 * kt + 8 * g + i;
          v[i] = (short)bf16bits(w2g[k * HD + col]);
        }
        B2[ntl][kt] = v;
      }
    }
  }
  float b1v[2], bFv[2];
  #pragma unroll
  for (int ntl = 0; ntl < 2; ++ntl) {
    int col = (2 * wv + ntl) * 16 + c;
    b1v[ntl] = TWO ? b1g[col] : 0.0f;
    bFv[ntl] = bFg[col];
  }

  for (int tile = blockIdx.x; tile < NTILES; tile += gridDim.x) {
    const unsigned short* afr = afr_g + (size_t)tile * 4096;
    f32x4 acc[4][2];
    #pragma unroll
    for (int mt = 0; mt < 4; ++mt) {
      acc[mt][0] = (f32x4){0.f, 0.f, 0.f, 0.f};
      acc[mt][1] = (f32x4){0.f, 0.f, 0.f, 0.f};
    }
    #pragma unroll
    for (int kt = 0; kt < 2; ++kt) {
      #pragma unroll
      for (int mt = 0; mt < 4; ++mt) {
        short8 a = *(const short8*)(afr + ((size_t)((4 * kt + g) * 64 + (16 * mt + c))) * 8);
        acc[mt][0] = mfma16(a, B1[0][kt], acc[mt][0]);
        acc[mt][1] = mfma16(a, B1[1][kt], acc[mt][1]);
      }
    }
    if (TWO) {
      #pragma unroll
      for (int mt = 0; mt < 4; ++mt) {
        #pragma unroll
        for (int ntl = 0; ntl < 2; ++ntl) {
          int ch = (2 * wv + ntl) * 16 + c;
          #pragma unroll
          for (int r = 0; r < 4; ++r) {
            int e = 16 * mt + 4 * g + r;
            float v = silu_f(acc[mt][ntl][r] + b1v[ntl]);
            s_u[((ch >> 3) * 64 + e) * 8 + (ch & 7)] = bf16bits(v);
          }
        }
      }
      __syncthreads();
      #pragma unroll
      for (int mt = 0; mt < 4; ++mt) {
        acc[mt][0] = (f32x4){0.f, 0.f, 0.f, 0.f};
        acc[mt][1] = (f32x4){0.f, 0.f, 0.f, 0.f};
      }
      #pragma unroll
      for (int kt = 0; kt < 4; ++kt) {
        #pragma unroll
        for (int mt = 0; mt < 4; ++mt) {
          short8 a = *(const short8*)(s_u + ((4 * kt + g) * 64 + (16 * mt + c)) * 8);
          acc[mt][0] = mfma16(a, B2[0][kt], acc[mt][0]);
          acc[mt][1] = mfma16(a, B2[1][kt], acc[mt][1]);
        }
      }
      __syncthreads();
    }
    #pragma unroll
    for (int mt = 0; mt < 4; ++mt) {
      float Cv[4];
      #pragma unroll
      for (int r = 0; r < 4; ++r) Cv[r] = scale_e[tile * 64 + 16 * mt + 4 * g + r];
      #pragma unroll
      for (int ntl = 0; ntl < 2; ++ntl) {
        int ch = (2 * wv + ntl) * 16 + c;
        #pragma unroll
        for (int r = 0; r < 4; ++r) {
          int e = 16 * mt + 4 * g + r;
          float v = (acc[mt][ntl][r] + bFv[ntl]) * Cv[r];
          s_u[e * WPAD + ch] = bf16bits(v);
        }
      }
    }
    __syncthreads();
    {
      short8* dst = (short8*)(Wout + (size_t)tile * 8192);
      #pragma unroll
      for (int k2 = 0; k2 < 4; ++k2) {
        int m = t + 256 * k2;
        int e = m >> 4, chunk = m & 15;
        dst[m] = *(const short8*)(s_u + e * WPAD + chunk * 8);
      }
    }
    __syncthreads();
  }
}

// ---------------- Pass B: segment sum (R8 form) ----------------
__global__ __launch_bounds__(256)
void k_segsum(const unsigned short* __restrict__ Wst, const float* __restrict__ h,
              const int* __restrict__ rowptr, const int* __restrict__ srcj,
              float* __restrict__ out) {
  int t = threadIdx.x, wv = t >> 6, lane = t & 63;
  int n = blockIdx.x * 4 + wv;
  if (n >= N_NODES) return;
  int half = lane >> 5;
  int q = lane & 31;
  int beg = rowptr[n], end = rowptr[n + 1];
  float a0 = 0.f, a1 = 0.f, a2 = 0.f, a3 = 0.f;
  #pragma unroll 4
  for (int p = beg + half; p < end; p += 2) {
    int j = srcj[p];
    uint2 wb = *(const uint2*)(Wst + (size_t)p * 128 + 4 * q);
    float4 hv = *(const float4*)(h + (size_t)j * 128 + 4 * q);
    a0 += hv.x * bfu_hi(wb.x << 16);
    a1 += hv.y * bfu_hi(wb.x & 0xffff0000u);
    a2 += hv.z * bfu_hi(wb.y << 16);
    a3 += hv.w * bfu_hi(wb.y & 0xffff0000u);
  }
  a0 += __shfl_xor(a0, 32, 64);
  a1 += __shfl_xor(a1, 32, 64);
  a2 += __shfl_xor(a2, 32, 64);
  a3 += __shfl_xor(a3, 32, 64);
  if (half == 0) {
    *(float4*)(out + (size_t)n * 128 + 4 * q) = make_float4(a0, a1, a2, a3);
  }
}

// ---------------- MFMA node GEMM, split-bf16, 32-row blocks ----------------
// LIN1: after writing out, also compute hout = out_block @ W3 (no bias) via
// the u-staging D-frag->A-frag relayout (same arithmetic as standalone lin1).
template <int KT, bool HASB, bool SILU, bool ADD, bool LIN1>
__global__ __launch_bounds__(512)
void k_nmfma(const float* __restrict__ in1, const float* __restrict__ in2,
             const float* __restrict__ Wg, const float* __restrict__ bias,
             float* __restrict__ out,
             const float* __restrict__ W3, float* __restrict__ hout) {
  __shared__ unsigned short s_h[LIN1 ? 4096 : 8];
  __shared__ unsigned short s_l[LIN1 ? 4096 : 8];
  int t = threadIdx.x;
  int wv = t >> 6, lane = t & 63;
  int c = lane & 15, g = lane >> 4;
  int col = 16 * wv + c;
  int n0 = blockIdx.x * 32;

  short8 Bh[KT], Bl[KT];
  #pragma unroll
  for (int kt = 0; kt < KT; ++kt) {
    short8 h, l;
    #pragma unroll
    for (int i = 0; i < 8; ++i) {
      int k = 32 * kt + 8 * g + i;
      float w = Wg[(size_t)k * HD + col];
      unsigned short hb = bf16bits(w);
      h[i] = (short)hb;
      l[i] = (short)bf16bits(w - bfu_hi((unsigned int)hb << 16));
    }
    Bh[kt] = h; Bl[kt] = l;
  }

  f32x4 acc[2];
  acc[0] = (f32x4){0.f, 0.f, 0.f, 0.f};
  acc[1] = (f32x4){0.f, 0.f, 0.f, 0.f};

  #pragma unroll
  for (int kt = 0; kt < KT; ++kt) {
    const float* in = (KT == 8 && kt >= 4) ? in2 : in1;
    int koff = (kt & 3) * 32 + 8 * g;
    #pragma unroll
    for (int mt = 0; mt < 2; ++mt) {
      int row = n0 + 16 * mt + c;
      int rowc = row < N_NODES ? row : N_NODES - 1;
      short8 ah, al;
      split8(in + (size_t)rowc * HD + koff, ah, al);
      acc[mt] = mfma16(ah, Bh[kt], acc[mt]);
      acc[mt] = mfma16(al, Bh[kt], acc[mt]);
      acc[mt] = mfma16(ah, Bl[kt], acc[mt]);
    }
  }
  __syncthreads();   // all reads done before any in-place store
  float bv = HASB ? bias[col] : 0.0f;
  #pragma unroll
  for (int mt = 0; mt < 2; ++mt) {
    #pragma unroll
    for (int r = 0; r < 4; ++r) {
      int row = n0 + 16 * mt + 4 * g + r;
      if (row < N_NODES) {
        float v = acc[mt][r] + bv;
        if (SILU) v = silu_f(v);
        if (ADD) v += out[(size_t)row * HD + col];
        out[(size_t)row * HD + col] = v;
        if (LIN1) {
          int e = 16 * mt + 4 * g + r;
          unsigned short hb = bf16bits(v);
          unsigned short lb = bf16bits(v - bfu_hi((unsigned int)hb << 16));
          int idx = ((col >> 3) * 32 + e) * 8 + (col & 7);
          s_h[idx] = hb;
          s_l[idx] = lb;
        }
      }
    }
  }
  if (LIN1) {
    __syncthreads();
    short8 B3h[4], B3l[4];
    #pragma unroll
    for (int kt = 0; kt < 4; ++kt) {
      short8 h, l;
      #pragma unroll
      for (int i = 0; i < 8; ++i) {
        int k = 32 * kt + 8 * g + i;
        float w = W3[(size_t)k * HD + col];
        unsigned short hb = bf16bits(w);
        h[i] = (short)hb;
        l[i] = (short)bf16bits(w - bfu_hi((unsigned int)hb << 16));
      }
      B3h[kt] = h; B3l[kt] = l;
    }
    f32x4 acc3[2];
    acc3[0] = (f32x4){0.f, 0.f, 0.f, 0.f};
    acc3[1] = (f32x4){0.f, 0.f, 0.f, 0.f};
    #pragma unroll
    for (int kt = 0; kt < 4; ++kt) {
      #pragma unroll
      for (int mt = 0; mt < 2; ++mt) {
        int idx = ((4 * kt + g) * 32 + (16 * mt + c)) * 8;
        short8 ah = *(const short8*)(s_h + idx);
        short8 al = *(const short8*)(s_l + idx);
        acc3[mt] = mfma16(ah, B3h[kt], acc3[mt]);
        acc3[mt] = mfma16(al, B3h[kt], acc3[mt]);
        acc3[mt] = mfma16(ah, B3l[kt], acc3[mt]);
      }
    }
    #pragma unroll
    for (int mt = 0; mt < 2; ++mt) {
      #pragma unroll
      for (int r = 0; r < 4; ++r) {
        int row = n0 + 16 * mt + 4 * g + r;
        if (row < N_NODES) hout[(size_t)row * HD + col] = acc3[mt][r];
      }
    }
  }
}

// ---------------- fused lin2+silu+lin+residual (+ next-layer lin1) ---------
template <bool LIN1>
__global__ __launch_bounds__(512)
void k_nmfma2(const float* __restrict__ in1,
              const float* __restrict__ W1, const float* __restrict__ b1,
              const float* __restrict__ W2, const float* __restrict__ b2,
              float* __restrict__ xout,
              const float* __restrict__ W3, float* __restrict__ hout) {
  __shared__ unsigned short s_uh[4096];
  __shared__ unsigned short s_ul[4096];
  int t = threadIdx.x;
  int wv = t >> 6, lane = t & 63;
  int c = lane & 15, g = lane >> 4;
  int col = 16 * wv + c;
  int n0 = blockIdx.x * 32;

  short8 B1h[4], B1l[4], B2h[4], B2l[4];
  #pragma unroll
  for (int kt = 0; kt < 4; ++kt) {
    short8 h1, l1, h2, l2;
    #pragma unroll
    for (int i = 0; i < 8; ++i) {
      int k = 32 * kt + 8 * g + i;
      float w = W1[(size_t)k * HD + col];
      unsigned short hb = bf16bits(w);
      h1[i] = (short)hb;
      l1[i] = (short)bf16bits(w - bfu_hi((unsigned int)hb << 16));
      float w2 = W2[(size_t)k * HD + col];
      unsigned short hb2 = bf16bits(w2);
      h2[i] = (short)hb2;
      l2[i] = (short)bf16bits(w2 - bfu_hi((unsigned int)hb2 << 16));
    }
    B1h[kt] = h1; B1l[kt] = l1; B2h[kt] = h2; B2l[kt] = l2;
  }
  float b1v = b1[col], b2v = b2[col];

  f32x4 acc[2];
  acc[0] = (f32x4){0.f, 0.f, 0.f, 0.f};
  acc[1] = (f32x4){0.f, 0.f, 0.f, 0.f};
  #pragma unroll
  for (int kt = 0; kt < 4; ++kt) {
    int koff = kt * 32 + 8 * g;
    #pragma unroll
    for (int mt = 0; mt < 2; ++mt) {
      int row = n0 + 16 * mt + c;
      int rowc = row < N_NODES ? row : N_NODES - 1;
      short8 ah, al;
      split8(in1 + (size_t)rowc * HD + koff, ah, al);
      acc[mt] = mfma16(ah, B1h[kt], acc[mt]);
      acc[mt] = mfma16(al, B1h[kt], acc[mt]);
      acc[mt] = mfma16(ah, B1l[kt], acc[mt]);
    }
  }
  #pragma unroll
  for (int mt = 0; mt < 2; ++mt) {
    #pragma unroll
    for (int r = 0; r < 4; ++r) {
      int e = 16 * mt + 4 * g + r;
      float v = silu_f(acc[mt][r] + b1v);
      unsigned short hb = bf16bits(v);
      unsigned short lb = bf16bits(v - bfu_hi((unsigned int)hb << 16));
      int idx = ((col >> 3) * 32 + e) * 8 + (col & 7);
      s_uh[idx] = hb;
      s_ul[idx] = lb;
    }
  }
  __syncthreads();
  acc[0] = (f32x4){0.f, 0.f, 0.f, 0.f};
  acc[1] = (f32x4){0.f, 0.f, 0.f, 0.f};
  #pragma unroll
  for (int kt = 0; kt < 4; ++kt) {
    #pragma unroll
    for (int mt = 0; mt < 2; ++mt) {
      int idx = ((4 * kt + g) * 32 + (16 * mt + c)) * 8;
      short8 ah = *(const short8*)(s_uh + idx);
      short8 al = *(const short8*)(s_ul + idx);
      acc[mt] = mfma16(ah, B2h[kt], acc[mt]);
      acc[mt] = mfma16(al, B2h[kt], acc[mt]);
      acc[mt] = mfma16(ah, B2l[kt], acc[mt]);
    }
  }
  __syncthreads();   // GEMM2 reads of s_u done; buffers free for x re-stage
  #pragma unroll
  for (int mt = 0; mt < 2; ++mt) {
    #pragma unroll
    for (int r = 0; r < 4; ++r) {
      int row = n0 + 16 * mt + 4 * g + r;
      if (row < N_NODES) {
        float v = xout[(size_t)row * HD + col] + acc[mt][r] + b2v;
        xout[(size_t)row * HD + col] = v;
        if (LIN1) {
          int e = 16 * mt + 4 * g + r;
          unsigned short hb = bf16bits(v);
          unsigned short lb = bf16bits(v - bfu_hi((unsigned int)hb << 16));
          int idx = ((col >> 3) * 32 + e) * 8 + (col & 7);
          s_uh[idx] = hb;
          s_ul[idx] = lb;
        }
      }
    }
  }
  if (LIN1) {
    __syncthreads();
    short8 B3h[4], B3l[4];
    #pragma unroll
    for (int kt = 0; kt < 4; ++kt) {
      short8 h, l;
      #pragma unroll
      for (int i = 0; i < 8; ++i) {
        int k = 32 * kt + 8 * g + i;
        float w = W3[(size_t)k * HD + col];
        unsigned short hb = bf16bits(w);
        h[i] = (short)hb;
        l[i] = (short)bf16bits(w - bfu_hi((unsigned int)hb << 16));
      }
      B3h[kt] = h; B3l[kt] = l;
    }
    f32x4 acc3[2];
    acc3[0] = (f32x4){0.f, 0.f, 0.f, 0.f};
    acc3[1] = (f32x4){0.f, 0.f, 0.f, 0.f};
    #pragma unroll
    for (int kt = 0; kt < 4; ++kt) {
      #pragma unroll
      for (int mt = 0; mt < 2; ++mt) {
        int idx = ((4 * kt + g) * 32 + (16 * mt + c)) * 8;
        short8 ah = *(const short8*)(s_uh + idx);
        short8 al = *(const short8*)(s_ul + idx);
        acc3[mt] = mfma16(ah, B3h[kt], acc3[mt]);
        acc3[mt] = mfma16(al, B3h[kt], acc3[mt]);
        acc3[mt] = mfma16(ah, B3l[kt], acc3[mt]);
      }
    }
    #pragma unroll
    for (int mt = 0; mt < 2; ++mt) {
      #pragma unroll
      for (int r = 0; r < 4; ++r) {
        int row = n0 + 16 * mt + 4 * g + r;
        if (row < N_NODES) hout[(size_t)row * HD + col] = acc3[mt][r];
      }
    }
  }
}

extern "C" void kernel_launch(void* const* d_in, const int* in_sizes, int n_in,
                              void* d_out, int out_size, void* d_ws, size_t ws_size,
                              hipStream_t stream) {
  const int* z = (const int*)d_in[0];
  const int* ei = (const int*)d_in[1];
  const float* ew = (const float*)d_in[2];
  const float* emb = (const float*)d_in[3];
  const float* means = (const float*)d_in[4];
  const float* betas = (const float*)d_in[5];
  const float* dp_w = (const float*)d_in[6];
  const float* dp_b = (const float*)d_in[7];
  const float* comb_w = (const float*)d_in[8];
  const float* comb_b = (const float*)d_in[9];
  const float* mlp_w1 = (const float*)d_in[10];
  const float* mlp_b1 = (const float*)d_in[11];
  const float* mlp_w2 = (const float*)d_in[12];
  const float* mlp_b2 = (const float*)d_in[13];
  const float* lin1_w = (const float*)d_in[14];
  const float* lin2_w = (const float*)d_in[15];
  const float* lin2_b = (const float*)d_in[16];
  const float* lin_w = (const float*)d_in[17];
  const float* lin_b = (const float*)d_in[18];
  float* x = (float*)d_out;

  int* rowptr = (int*)d_ws;                         // 20032
  int* deg = rowptr + 20032;                        // 20032
  int* cursor = deg + 20032;                        // 20032
  int* bsum = cursor + 20032;                       // 128
  int* boff = bsum + 128;                           // 128
  int* eids = boff + 128;                           // E
  int* srcj = eids + N_EDGES;                       // E
  float* Csrt = (float*)(srcj + N_EDGES);           // E
  float* Cinv = Csrt + N_EDGES;                     // E
  unsigned short* attr_fr = (unsigned short*)(Cinv + N_EDGES);   // E*64 bf16
  unsigned short* Wst = attr_fr + (size_t)N_EDGES * 64;          // E*128 bf16
  float* hbuf = (float*)(Wst + (size_t)N_EDGES * 128);           // N*128
  float* aggb = hbuf + (size_t)N_NODES * HD;                     // N*128

  hipMemsetAsync(deg, 0, N_NODES * sizeof(int), stream);
  k_hist<<<(N_EDGES + 255) / 256, 256, 0, stream>>>(ei, deg);
  k_bsum<<<SCAN_B, 256, 0, stream>>>(deg, bsum);
  k_bscan<<<1, 64, 0, stream>>>(bsum, boff, rowptr + N_NODES);
  k_scanout<<<SCAN_B, 256, 0, stream>>>(deg, boff, rowptr, cursor);
  k_scatter<<<(N_EDGES + 255) / 256, 256, 0, stream>>>(ei, cursor, eids);
  k_attr<<<NTILES * 2, 256, 0, stream>>>(ei, ew, eids, rowptr, means, betas,
                                         attr_fr, Csrt, Cinv, srcj);
  k_init<<<(N_NODES * 32 + 255) / 256, 256, 0, stream>>>(z, emb, x);

  // dp block: W = (attr@dp_w + dp_b)*C ; agg = segsum(x[j]*W)
  k_filter<false><<<2500, 256, 0, stream>>>(attr_fr, Csrt, dp_w, nullptr,
                                            nullptr, dp_b, Wst);
  k_segsum<<<5000, 256, 0, stream>>>(Wst, x, rowptr, srcj, aggb);
  // comb (+ fused lin1 of layer 0)
  k_nmfma<8, true, false, false, true><<<625, 512, 0, stream>>>(
      x, aggb, comb_w, comb_b, x, lin1_w, hbuf);

  for (int l = 0; l < NL; ++l) {
    k_filter<true><<<2500, 256, 0, stream>>>(
        attr_fr, Cinv,
        mlp_w1 + (size_t)l * RD * HD, mlp_b1 + (size_t)l * HD,
        mlp_w2 + (size_t)l * HD * HD, mlp_b2 + (size_t)l * HD, Wst);
    k_segsum<<<5000, 256, 0, stream>>>(Wst, hbuf, rowptr, srcj, aggb);
    if (l < NL - 1) {
      k_nmfma2<true><<<625, 512, 0, stream>>>(
          aggb, lin2_w + (size_t)l * HD * HD, lin2_b + (size_t)l * HD,
          lin_w + (size_t)l * HD * HD, lin_b + (size_t)l * HD, x,
          lin1_w + (size_t)(l + 1) * HD * HD, hbuf);
    } else {
      k_nmfma2<false><<<625, 512, 0, stream>>>(
          aggb, lin2_w + (size_t)l * HD * HD, lin2_b + (size_t)l * HD,
          lin_w + (size_t)l * HD * HD, lin_b + (size_t)l * HD, x,
          nullptr, nullptr);
    }
  }
}

// Round 17
// 740.203 us; speedup vs baseline: 1.2130x; 1.0187x over previous
//
#include <hip/hip_runtime.h>
#include <hip/hip_bf16.h>
#include <math.h>

#define N_NODES 20000
#define N_EDGES 320000
#define NTILES  5000   // N_EDGES / 64
#define HD 128
#define RD 50
#define NL 6
#define CUTV 5.0f
#define PI_F 3.14159265358979323846f
#define WPAD 132       // padded W-tile row (ushorts) to kill epilogue bank conflicts
#define SCAN_B 79      // ceil(N_NODES/256)

typedef __attribute__((ext_vector_type(8))) short short8;
typedef __attribute__((ext_vector_type(4))) float f32x4;

__device__ __forceinline__ float cutoff_f(float d) {
  float c = 0.5f * (__cosf(d * (PI_F / CUTV)) + 1.0f);
  return d < CUTV ? c : 0.0f;
}
// silu via fast v_rcp (x/(1+e^-x) div sequence is ~8 VALU ops; rcp+mul is 2)
__device__ __forceinline__ float silu_f(float x) {
  return x * __builtin_amdgcn_rcpf(1.0f + __expf(-x));
}
// native RNE float->bf16
__device__ __forceinline__ unsigned short bf16bits(float f) {
  union { __hip_bfloat16 b; unsigned short u; } cv;
  cv.b = __float2bfloat16(f);
  return cv.u;
}
__device__ __forceinline__ float bfu_hi(unsigned int bits_in_high) {
  union { unsigned int u; float f; } v; v.u = bits_in_high; return v.f;
}
__device__ __forceinline__ f32x4 mfma16(short8 a, short8 b, f32x4 c) {
  return __builtin_amdgcn_mfma_f32_16x16x32_bf16(a, b, c, 0, 0, 0);
}
// split 8 consecutive floats into hi/lo bf16 fragments
__device__ __forceinline__ void split8(const float* __restrict__ p,
                                       short8& h, short8& l) {
  float4 v0 = *(const float4*)p;
  float4 v1 = *(const float4*)(p + 4);
  float vv[8] = {v0.x, v0.y, v0.z, v0.w, v1.x, v1.y, v1.z, v1.w};
  #pragma unroll
  for (int i = 0; i < 8; ++i) {
    unsigned short hb = bf16bits(vv[i]);
    h[i] = (short)hb;
    l[i] = (short)bf16bits(vv[i] - bfu_hi((unsigned int)hb << 16));
  }
}

// ---------------- CSR build ----------------
__global__ void k_hist(const int* __restrict__ ei, int* __restrict__ deg) {
  int e = blockIdx.x * blockDim.x + threadIdx.x;
  if (e < N_EDGES) atomicAdd(&deg[ei[N_EDGES + e]], 1);
}

// parallel scan: block reduce -> tiny serial scan -> block scan-out
__global__ void k_bsum(const int* __restrict__ deg, int* __restrict__ bsum) {
  __shared__ int sdata[256];
  int b = blockIdx.x, t = threadIdx.x;
  int i = b * 256 + t;
  sdata[t] = (i < N_NODES) ? deg[i] : 0;
  __syncthreads();
  for (int off = 128; off > 0; off >>= 1) {
    if (t < off) sdata[t] += sdata[t + off];
    __syncthreads();
  }
  if (t == 0) bsum[b] = sdata[0];
}

__global__ void k_bscan(const int* __restrict__ bsum, int* __restrict__ boff,
                        int* __restrict__ rowptrN) {
  if (threadIdx.x == 0) {
    int run = 0;
    for (int b = 0; b < SCAN_B; ++b) { boff[b] = run; run += bsum[b]; }
    rowptrN[0] = run;   // = N_EDGES
  }
}

__global__ void k_scanout(const int* __restrict__ deg, const int* __restrict__ boff,
                          int* __restrict__ rowptr, int* __restrict__ cursor) {
  __shared__ int sdata[256];
  int b = blockIdx.x, t = threadIdx.x;
  int i = b * 256 + t;
  int v = (i < N_NODES) ? deg[i] : 0;
  sdata[t] = v;
  __syncthreads();
  for (int off = 1; off < 256; off <<= 1) {
    int add = (t >= off) ? sdata[t - off] : 0;
    __syncthreads();
    sdata[t] += add;
    __syncthreads();
  }
  if (i < N_NODES) {
    int excl = boff[b] + sdata[t] - v;
    rowptr[i] = excl;
    cursor[i] = excl;
  }
}

__global__ void k_scatter(const int* __restrict__ ei, int* __restrict__ cursor,
                          int* __restrict__ eids) {
  int e = blockIdx.x * blockDim.x + threadIdx.x;
  if (e < N_EDGES) {
    int i = ei[N_EDGES + e];
    int p = atomicAdd(&cursor[i], 1);
    eids[p] = e;
  }
}

// ---------------- x0 = emb[z] ----------------
__global__ void k_init(const int* __restrict__ z, const float* __restrict__ emb,
                       float* __restrict__ x) {
  int idx = blockIdx.x * blockDim.x + threadIdx.x;
  if (idx < N_NODES * 32) {
    int n = idx >> 5, c4 = idx & 31;
    float4 v = ((const float4*)emb)[z[n] * 32 + c4];
    ((float4*)x)[n * 32 + c4] = v;
  }
}

// ---------------- attr precompute: one thread per edge ----------------
__global__ __launch_bounds__(256)
void k_attr(const int* __restrict__ ei, const float* __restrict__ ew,
            const int* __restrict__ eids, const int* __restrict__ rowptr,
            const float* __restrict__ means, const float* __restrict__ betas,
            unsigned short* __restrict__ attr_fr, float* __restrict__ Csrt,
            float* __restrict__ Cinv, int* __restrict__ srcj) {
  int p = blockIdx.x * 256 + threadIdx.x;
  if (p >= N_EDGES) return;
  int tile = p >> 6, e = p & 63;
  int eo = eids[p];
  float d = ew[eo];
  float C = cutoff_f(d);
  float ex = __expf(-d);
  unsigned short* base = attr_fr + (size_t)tile * 4096 + e * 8;
  #pragma unroll
  for (int kg = 0; kg < 8; ++kg) {
    short8 out;
    #pragma unroll
    for (int i = 0; i < 8; ++i) {
      int k = kg * 8 + i;
      float v = 0.0f;
      if (k < RD) {
        float em = ex - means[k];
        v = C * __expf(-betas[k] * em * em);
      }
      out[i] = (short)bf16bits(v);
    }
    *(short8*)(base + kg * 512) = out;
  }
  Csrt[p] = C;
  srcj[p] = ei[eo];
  int dn = ei[N_EDGES + eo];
  int dg = rowptr[dn + 1] - rowptr[dn];
  Cinv[p] = C / (float)(dg > 0 ? dg : 1);
}

// ---------------- Pass A: per-edge filter via MFMA (R13 proven form) -------
template <bool TWO>
__global__ __launch_bounds__(256, 4)
void k_filter(const unsigned short* __restrict__ afr_g,
              const float* __restrict__ scale_e,
              const float* __restrict__ w1g, const float* __restrict__ b1g,
              const float* __restrict__ w2g, const float* __restrict__ bFg,
              unsigned short* __restrict__ Wout) {
  __shared__ unsigned short s_u[64 * WPAD];
  int t = threadIdx.x;
  int wv = t >> 6, lane = t & 63;
  int c = lane & 15, g = lane >> 4;

  short8 B1[2][2];
  #pragma unroll
  for (int ntl = 0; ntl < 2; ++ntl) {
    int col = (2 * wv + ntl) * 16 + c;
    #pragma unroll
    for (int kt = 0; kt < 2; ++kt) {
      short8 v;
      #pragma unroll
      for (int i = 0; i < 8; ++i) {
        int k = 32 * kt + 8 * g + i;
        v[i] = (k < RD) ? (short)bf16bits(w1g[k * HD + col]) : (short)0;
      }
      B1[ntl][kt] = v;
    }
  }
  short8 B2[2][4];
  if (TWO) {
    #pragma unroll
    for (int ntl = 0; ntl < 2; ++ntl) {
      int col = (2 * wv + ntl) * 16 + c;
      #pragma unroll
      for (int kt = 0; kt < 4; ++kt) {
        short8 v;
        #pragma unroll
        for (int i = 0; i < 8; ++i) {
          int k = 32 * kt + 8 * g + i;
          v[i] = (short)bf16bits(w2g[k * HD + col]);
        }
        B2[ntl][kt] = v;
      }
    }
  }
  float b1v[2], bFv[2];
  #pragma unroll
  for (int ntl = 0; ntl < 2; ++ntl) {
    int col = (2 * wv + ntl) * 16 + c;
    b1v[ntl] = TWO ? b1g[col] : 0.0f;
    bFv[ntl] = bFg[col];
  }

  for (int tile = blockIdx.x; tile < NTILES; tile += gridDim.x) {
    const unsigned short* afr = afr_g + (size_t)tile * 4096;
    f32x4 acc[4][2];
    #pragma unroll
    for (int mt = 0; mt < 4; ++mt) {
      acc[mt][0] = (f32x4){0.f, 0.f, 0.f, 0.f};
      acc[mt][1] = (f32x4){0.f, 0.f, 0.f, 0.f};
    }
    #pragma unroll
    for (int kt = 0; kt < 2; ++kt) {
      #pragma unroll
      for (int mt = 0; mt < 4; ++mt) {
        short8 a = *(const short8*)(afr + ((size_t)((4 * kt + g) * 64 + (16 * mt + c))) * 8);
        acc[mt][0] = mfma16(a, B1[0][kt], acc[mt][0]);
        acc[mt][1] = mfma16(a, B1[1][kt], acc[mt][1]);
      }
    }
    if (TWO) {
      #pragma unroll
      for (int mt = 0; mt < 4; ++mt) {
        #pragma unroll
        for (int ntl = 0; ntl < 2; ++ntl) {
          int ch = (2 * wv + ntl) * 16 + c;
          #pragma unroll
          for (int r = 0; r < 4; ++r) {
            int e = 16 * mt + 4 * g + r;
            float v = silu_f(acc[mt][ntl][r] + b1v[ntl]);
            s_u[((ch >> 3) * 64 + e) * 8 + (ch & 7)] = bf16bits(v);
          }
        }
      }
      __syncthreads();
      #pragma unroll
      for (int mt = 0; mt < 4; ++mt) {
        acc[mt][0] = (f32x4){0.f, 0.f, 0.f, 0.f};
        acc[mt][1] = (f32x4){0.f, 0.f, 0.f, 0.f};
      }
      #pragma unroll
      for (int kt = 0; kt < 4; ++kt) {
        #pragma unroll
        for (int mt = 0; mt < 4; ++mt) {
          short8 a = *(const short8*)(s_u + ((4 * kt + g) * 64 + (16 * mt + c)) * 8);
          acc[mt][0] = mfma16(a, B2[0][kt], acc[mt][0]);
          acc[mt][1] = mfma16(a, B2[1][kt], acc[mt][1]);
        }
      }
      __syncthreads();
    }
    #pragma unroll
    for (int mt = 0; mt < 4; ++mt) {
      float Cv[4];
      #pragma unroll
      for (int r = 0; r < 4; ++r) Cv[r] = scale_e[tile * 64 + 16 * mt + 4 * g + r];
      #pragma unroll
      for (int ntl = 0; ntl < 2; ++ntl) {
        int ch = (2 * wv + ntl) * 16 + c;
        #pragma unroll
        for (int r = 0; r < 4; ++r) {
          int e = 16 * mt + 4 * g + r;
          float v = (acc[mt][ntl][r] + bFv[ntl]) * Cv[r];
          s_u[e * WPAD + ch] = bf16bits(v);
        }
      }
    }
    __syncthreads();
    {
      short8* dst = (short8*)(Wout + (size_t)tile * 8192);
      #pragma unroll
      for (int k2 = 0; k2 < 4; ++k2) {
        int m = t + 256 * k2;
        int e = m >> 4, chunk = m & 15;
        dst[m] = *(const short8*)(s_u + e * WPAD + chunk * 8);
      }
    }
    __syncthreads();
  }
}

// ---------------- Pass B: segment sum (4 edge slots, uint4 W reads) --------
__global__ __launch_bounds__(256)
void k_segsum(const unsigned short* __restrict__ Wst, const float* __restrict__ h,
              const int* __restrict__ rowptr, const int* __restrict__ srcj,
              float* __restrict__ out) {
  int t = threadIdx.x, wv = t >> 6, lane = t & 63;
  int n = blockIdx.x * 4 + wv;
  if (n >= N_NODES) return;
  int par = lane >> 4;       // edge slot 0..3
  int q8 = lane & 15;        // col group: cols 8q8..8q8+7
  int beg = rowptr[n], end = rowptr[n + 1];
  float a0 = 0.f, a1 = 0.f, a2 = 0.f, a3 = 0.f;
  float a4 = 0.f, a5 = 0.f, a6 = 0.f, a7 = 0.f;
  #pragma unroll 2
  for (int p = beg + par; p < end; p += 4) {
    int j = srcj[p];
    uint4 wb = *(const uint4*)(Wst + (size_t)p * 128 + 8 * q8);
    float4 h0 = *(const float4*)(h + (size_t)j * 128 + 8 * q8);
    float4 h1 = *(const float4*)(h + (size_t)j * 128 + 8 * q8 + 4);
    a0 += h0.x * bfu_hi(wb.x << 16);
    a1 += h0.y * bfu_hi(wb.x & 0xffff0000u);
    a2 += h0.z * bfu_hi(wb.y << 16);
    a3 += h0.w * bfu_hi(wb.y & 0xffff0000u);
    a4 += h1.x * bfu_hi(wb.z << 16);
    a5 += h1.y * bfu_hi(wb.z & 0xffff0000u);
    a6 += h1.z * bfu_hi(wb.w << 16);
    a7 += h1.w * bfu_hi(wb.w & 0xffff0000u);
  }
  // reduce across 4 edge slots
  a0 += __shfl_xor(a0, 16, 64); a0 += __shfl_xor(a0, 32, 64);
  a1 += __shfl_xor(a1, 16, 64); a1 += __shfl_xor(a1, 32, 64);
  a2 += __shfl_xor(a2, 16, 64); a2 += __shfl_xor(a2, 32, 64);
  a3 += __shfl_xor(a3, 16, 64); a3 += __shfl_xor(a3, 32, 64);
  a4 += __shfl_xor(a4, 16, 64); a4 += __shfl_xor(a4, 32, 64);
  a5 += __shfl_xor(a5, 16, 64); a5 += __shfl_xor(a5, 32, 64);
  a6 += __shfl_xor(a6, 16, 64); a6 += __shfl_xor(a6, 32, 64);
  a7 += __shfl_xor(a7, 16, 64); a7 += __shfl_xor(a7, 32, 64);
  if (par == 0) {
    *(float4*)(out + (size_t)n * 128 + 8 * q8) = make_float4(a0, a1, a2, a3);
    *(float4*)(out + (size_t)n * 128 + 8 * q8 + 4) = make_float4(a4, a5, a6, a7);
  }
}

// ---------------- MFMA node GEMM, split-bf16, 32-row blocks ----------------
// LIN1: after writing out, also compute hout = out_block @ W3 (no bias) via
// the u-staging D-frag->A-frag relayout (same arithmetic as standalone lin1).
template <int KT, bool HASB, bool SILU, bool ADD, bool LIN1>
__global__ __launch_bounds__(512)
void k_nmfma(const float* __restrict__ in1, const float* __restrict__ in2,
             const float* __restrict__ Wg, const float* __restrict__ bias,
             float* __restrict__ out,
             const float* __restrict__ W3, float* __restrict__ hout) {
  __shared__ unsigned short s_h[LIN1 ? 4096 : 8];
  __shared__ unsigned short s_l[LIN1 ? 4096 : 8];
  int t = threadIdx.x;
  int wv = t >> 6, lane = t & 63;
  int c = lane & 15, g = lane >> 4;
  int col = 16 * wv + c;
  int n0 = blockIdx.x * 32;

  short8 Bh[KT], Bl[KT];
  #pragma unroll
  for (int kt = 0; kt < KT; ++kt) {
    short8 h, l;
    #pragma unroll
    for (int i = 0; i < 8; ++i) {
      int k = 32 * kt + 8 * g + i;
      float w = Wg[(size_t)k * HD + col];
      unsigned short hb = bf16bits(w);
      h[i] = (short)hb;
      l[i] = (short)bf16bits(w - bfu_hi((unsigned int)hb << 16));
    }
    Bh[kt] = h; Bl[kt] = l;
  }

  f32x4 acc[2];
  acc[0] = (f32x4){0.f, 0.f, 0.f, 0.f};
  acc[1] = (f32x4){0.f, 0.f, 0.f, 0.f};

  #pragma unroll
  for (int kt = 0; kt < KT; ++kt) {
    const float* in = (KT == 8 && kt >= 4) ? in2 : in1;
    int koff = (kt & 3) * 32 + 8 * g;
    #pragma unroll
    for (int mt = 0; mt < 2; ++mt) {
      int row = n0 + 16 * mt + c;
      int rowc = row < N_NODES ? row : N_NODES - 1;
      short8 ah, al;
      split8(in + (size_t)rowc * HD + koff, ah, al);
      acc[mt] = mfma16(ah, Bh[kt], acc[mt]);
      acc[mt] = mfma16(al, Bh[kt], acc[mt]);
      acc[mt] = mfma16(ah, Bl[kt], acc[mt]);
    }
  }
  __syncthreads();   // all reads done before any in-place store
  float bv = HASB ? bias[col] : 0.0f;
  #pragma unroll
  for (int mt = 0; mt < 2; ++mt) {
    #pragma unroll
    for (int r = 0; r < 4; ++r) {
      int row = n0 + 16 * mt + 4 * g + r;
      if (row < N_NODES) {
        float v = acc[mt][r] + bv;
        if (SILU) v = silu_f(v);
        if (ADD) v += out[(size_t)row * HD + col];
        out[(size_t)row * HD + col] = v;
        if (LIN1) {
          int e = 16 * mt + 4 * g + r;
          unsigned short hb = bf16bits(v);
          unsigned short lb = bf16bits(v - bfu_hi((unsigned int)hb << 16));
          int idx = ((col >> 3) * 32 + e) * 8 + (col & 7);
          s_h[idx] = hb;
          s_l[idx] = lb;
        }
      }
    }
  }
  if (LIN1) {
    __syncthreads();
    short8 B3h[4], B3l[4];
    #pragma unroll
    for (int kt = 0; kt < 4; ++kt) {
      short8 h, l;
      #pragma unroll
      for (int i = 0; i < 8; ++i) {
        int k = 32 * kt + 8 * g + i;
        float w = W3[(size_t)k * HD + col];
        unsigned short hb = bf16bits(w);
        h[i] = (short)hb;
        l[i] = (short)bf16bits(w - bfu_hi((unsigned int)hb << 16));
      }
      B3h[kt] = h; B3l[kt] = l;
    }
    f32x4 acc3[2];
    acc3[0] = (f32x4){0.f, 0.f, 0.f, 0.f};
    acc3[1] = (f32x4){0.f, 0.f, 0.f, 0.f};
    #pragma unroll
    for (int kt = 0; kt < 4; ++kt) {
      #pragma unroll
      for (int mt = 0; mt < 2; ++mt) {
        int idx = ((4 * kt + g) * 32 + (16 * mt + c)) * 8;
        short8 ah = *(const short8*)(s_h + idx);
        short8 al = *(const short8*)(s_l + idx);
        acc3[mt] = mfma16(ah, B3h[kt], acc3[mt]);
        acc3[mt] = mfma16(al, B3h[kt], acc3[mt]);
        acc3[mt] = mfma16(ah, B3l[kt], acc3[mt]);
      }
    }
    #pragma unroll
    for (int mt = 0; mt < 2; ++mt) {
      #pragma unroll
      for (int r = 0; r < 4; ++r) {
        int row = n0 + 16 * mt + 4 * g + r;
        if (row < N_NODES) hout[(size_t)row * HD + col] = acc3[mt][r];
      }
    }
  }
}

// ---------------- fused lin2+silu+lin+residual (+ next-layer lin1) ---------
template <bool LIN1>
__global__ __launch_bounds__(512)
void k_nmfma2(const float* __restrict__ in1,
              const float* __restrict__ W1, const float* __restrict__ b1,
              const float* __restrict__ W2, const float* __restrict__ b2,
              float* __restrict__ xout,
              const float* __restrict__ W3, float* __restrict__ hout) {
  __shared__ unsigned short s_uh[4096];
  __shared__ unsigned short s_ul[4096];
  int t = threadIdx.x;
  int wv = t >> 6, lane = t & 63;
  int c = lane & 15, g = lane >> 4;
  int col = 16 * wv + c;
  int n0 = blockIdx.x * 32;

  short8 B1h[4], B1l[4], B2h[4], B2l[4];
  #pragma unroll
  for (int kt = 0; kt < 4; ++kt) {
    short8 h1, l1, h2, l2;
    #pragma unroll
    for (int i = 0; i < 8; ++i) {
      int k = 32 * kt + 8 * g + i;
      float w = W1[(size_t)k * HD + col];
      unsigned short hb = bf16bits(w);
      h1[i] = (short)hb;
      l1[i] = (short)bf16bits(w - bfu_hi((unsigned int)hb << 16));
      float w2 = W2[(size_t)k * HD + col];
      unsigned short hb2 = bf16bits(w2);
      h2[i] = (short)hb2;
      l2[i] = (short)bf16bits(w2 - bfu_hi((unsigned int)hb2 << 16));
    }
    B1h[kt] = h1; B1l[kt] = l1; B2h[kt] = h2; B2l[kt] = l2;
  }
  float b1v = b1[col], b2v = b2[col];

  f32x4 acc[2];
  acc[0] = (f32x4){0.f, 0.f, 0.f, 0.f};
  acc[1] = (f32x4){0.f, 0.f, 0.f, 0.f};
  #pragma unroll
  for (int kt = 0; kt < 4; ++kt) {
    int koff = kt * 32 + 8 * g;
    #pragma unroll
    for (int mt = 0; mt < 2; ++mt) {
      int row = n0 + 16 * mt + c;
      int rowc = row < N_NODES ? row : N_NODES - 1;
      short8 ah, al;
      split8(in1 + (size_t)rowc * HD + koff, ah, al);
      acc[mt] = mfma16(ah, B1h[kt], acc[mt]);
      acc[mt] = mfma16(al, B1h[kt], acc[mt]);
      acc[mt] = mfma16(ah, B1l[kt], acc[mt]);
    }
  }
  #pragma unroll
  for (int mt = 0; mt < 2; ++mt) {
    #pragma unroll
    for (int r = 0; r < 4; ++r) {
      int e = 16 * mt + 4 * g + r;
      float v = silu_f(acc[mt][r] + b1v);
      unsigned short hb = bf16bits(v);
      unsigned short lb = bf16bits(v - bfu_hi((unsigned int)hb << 16));
      int idx = ((col >> 3) * 32 + e) * 8 + (col & 7);
      s_uh[idx] = hb;
      s_ul[idx] = lb;
    }
  }
  __syncthreads();
  acc[0] = (f32x4){0.f, 0.f, 0.f, 0.f};
  acc[1] = (f32x4){0.f, 0.f, 0.f, 0.f};
  #pragma unroll
  for (int kt = 0; kt < 4; ++kt) {
    #pragma unroll
    for (int mt = 0; mt < 2; ++mt) {
      int idx = ((4 * kt + g) * 32 + (16 * mt + c)) * 8;
      short8 ah = *(const short8*)(s_uh + idx);
      short8 al = *(const short8*)(s_ul + idx);
      acc[mt] = mfma16(ah, B2h[kt], acc[mt]);
      acc[mt] = mfma16(al, B2h[kt], acc[mt]);
      acc[mt] = mfma16(ah, B2l[kt], acc[mt]);
    }
  }
  __syncthreads();   // GEMM2 reads of s_u done; buffers free for x re-stage
  #pragma unroll
  for (int mt = 0; mt < 2; ++mt) {
    #pragma unroll
    for (int r = 0; r < 4; ++r) {
      int row = n0 + 16 * mt + 4 * g + r;
      if (row < N_NODES) {
        float v = xout[(size_t)row * HD + col] + acc[mt][r] + b2v;
        xout[(size_t)row * HD + col] = v;
        if (LIN1) {
          int e = 16 * mt + 4 * g + r;
          unsigned short hb = bf16bits(v);
          unsigned short lb = bf16bits(v - bfu_hi((unsigned int)hb << 16));
          int idx = ((col >> 3) * 32 + e) * 8 + (col & 7);
          s_uh[idx] = hb;
          s_ul[idx] = lb;
        }
      }
    }
  }
  if (LIN1) {
    __syncthreads();
    short8 B3h[4], B3l[4];
    #pragma unroll
    for (int kt = 0; kt < 4; ++kt) {
      short8 h, l;
      #pragma unroll
      for (int i = 0; i < 8; ++i) {
        int k = 32 * kt + 8 * g + i;
        float w = W3[(size_t)k * HD + col];
        unsigned short hb = bf16bits(w);
        h[i] = (short)hb;
        l[i] = (short)bf16bits(w - bfu_hi((unsigned int)hb << 16));
      }
      B3h[kt] = h; B3l[kt] = l;
    }
    f32x4 acc3[2];
    acc3[0] = (f32x4){0.f, 0.f, 0.f, 0.f};
    acc3[1] = (f32x4){0.f, 0.f, 0.f, 0.f};
    #pragma unroll
    for (int kt = 0; kt < 4; ++kt) {
      #pragma unroll
      for (int mt = 0; mt < 2; ++mt) {
        int idx = ((4 * kt + g) * 32 + (16 * mt + c)) * 8;
        short8 ah = *(const short8*)(s_uh + idx);
        short8 al = *(const short8*)(s_ul + idx);
        acc3[mt] = mfma16(ah, B3h[kt], acc3[mt]);
        acc3[mt] = mfma16(al, B3h[kt], acc3[mt]);
        acc3[mt] = mfma16(ah, B3l[kt], acc3[mt]);
      }
    }
    #pragma unroll
    for (int mt = 0; mt < 2; ++mt) {
      #pragma unroll
      for (int r = 0; r < 4; ++r) {
        int row = n0 + 16 * mt + 4 * g + r;
        if (row < N_NODES) hout[(size_t)row * HD + col] = acc3[mt][r];
      }
    }
  }
}

extern "C" void kernel_launch(void* const* d_in, const int* in_sizes, int n_in,
                              void* d_out, int out_size, void* d_ws, size_t ws_size,
                              hipStream_t stream) {
  const int* z = (const int*)d_in[0];
  const int* ei = (const int*)d_in[1];
  const float* ew = (const float*)d_in[2];
  const float* emb = (const float*)d_in[3];
  const float* means = (const float*)d_in[4];
  const float* betas = (const float*)d_in[5];
  const float* dp_w = (const float*)d_in[6];
  const float* dp_b = (const float*)d_in[7];
  const float* comb_w = (const float*)d_in[8];
  const float* comb_b = (const float*)d_in[9];
  const float* mlp_w1 = (const float*)d_in[10];
  const float* mlp_b1 = (const float*)d_in[11];
  const float* mlp_w2 = (const float*)d_in[12];
  const float* mlp_b2 = (const float*)d_in[13];
  const float* lin1_w = (const float*)d_in[14];
  const float* lin2_w = (const float*)d_in[15];
  const float* lin2_b = (const float*)d_in[16];
  const float* lin_w = (const float*)d_in[17];
  const float* lin_b = (const float*)d_in[18];
  float* x = (float*)d_out;

  int* rowptr = (int*)d_ws;                         // 20032
  int* deg = rowptr + 20032;                        // 20032
  int* cursor = deg + 20032;                        // 20032
  int* bsum = cursor + 20032;                       // 128
  int* boff = bsum + 128;                           // 128
  int* eids = boff + 128;                           // E
  int* srcj = eids + N_EDGES;                       // E
  float* Csrt = (float*)(srcj + N_EDGES);           // E
  float* Cinv = Csrt + N_EDGES;                     // E
  unsigned short* attr_fr = (unsigned short*)(Cinv + N_EDGES);   // E*64 bf16
  unsigned short* Wst = attr_fr + (size_t)N_EDGES * 64;          // E*128 bf16
  float* hbuf = (float*)(Wst + (size_t)N_EDGES * 128);           // N*128
  float* aggb = hbuf + (size_t)N_NODES * HD;                     // N*128

  hipMemsetAsync(deg, 0, N_NODES * sizeof(int), stream);
  k_hist<<<(N_EDGES + 255) / 256, 256, 0, stream>>>(ei, deg);
  k_bsum<<<SCAN_B, 256, 0, stream>>>(deg, bsum);
  k_bscan<<<1, 64, 0, stream>>>(bsum, boff, rowptr + N_NODES);
  k_scanout<<<SCAN_B, 256, 0, stream>>>(deg, boff, rowptr, cursor);
  k_scatter<<<(N_EDGES + 255) / 256, 256, 0, stream>>>(ei, cursor, eids);
  k_attr<<<(N_EDGES + 255) / 256, 256, 0, stream>>>(ei, ew, eids, rowptr, means,
                                                    betas, attr_fr, Csrt, Cinv, srcj);
  k_init<<<(N_NODES * 32 + 255) / 256, 256, 0, stream>>>(z, emb, x);

  // dp block: W = (attr@dp_w + dp_b)*C ; agg = segsum(x[j]*W)
  k_filter<false><<<2500, 256, 0, stream>>>(attr_fr, Csrt, dp_w, nullptr,
                                            nullptr, dp_b, Wst);
  k_segsum<<<5000, 256, 0, stream>>>(Wst, x, rowptr, srcj, aggb);
  // comb (+ fused lin1 of layer 0)
  k_nmfma<8, true, false, false, true><<<625, 512, 0, stream>>>(
      x, aggb, comb_w, comb_b, x, lin1_w, hbuf);

  for (int l = 0; l < NL; ++l) {
    k_filter<true><<<2500, 256, 0, stream>>>(
        attr_fr, Cinv,
        mlp_w1 + (size_t)l * RD * HD, mlp_b1 + (size_t)l * HD,
        mlp_w2 + (size_t)l * HD * HD, mlp_b2 + (size_t)l * HD, Wst);
    k_segsum<<<5000, 256, 0, stream>>>(Wst, hbuf, rowptr, srcj, aggb);
    if (l < NL - 1) {
      k_nmfma2<true><<<625, 512, 0, stream>>>(
          aggb, lin2_w + (size_t)l * HD * HD, lin2_b + (size_t)l * HD,
          lin_w + (size_t)l * HD * HD, lin_b + (size_t)l * HD, x,
          lin1_w + (size_t)(l + 1) * HD * HD, hbuf);
    } else {
      k_nmfma2<false><<<625, 512, 0, stream>>>(
          aggb, lin2_w + (size_t)l * HD * HD, lin2_b + (size_t)l * HD,
          lin_w + (size_t)l * HD * HD, lin_b + (size_t)l * HD, x,
          nullptr, nullptr);
    }
  }
}